// Round 1
// baseline (12331.104 us; speedup 1.0000x reference)
//
#include <hip/hip_runtime.h>
#include <hip/hip_bf16.h>

typedef __hip_bfloat16 bf16;

#define DEV __device__ __forceinline__

DEV float to_f32(float x) { return x; }
DEV float to_f32(bf16 x) { return __bfloat162float(x); }
DEV void store_c(float* p, float v) { *p = v; }
DEV void store_c(bf16* p, float v) { *p = __float2bfloat16(v); }
DEV float sigmf(float x) { return 1.f / (1.f + __expf(-x)); }

// ---------------- embedding gather ----------------
__global__ void gather_embed(const int* __restrict__ idx, const float* __restrict__ embed,
                             float* __restrict__ out, int ntok) {
  int i = blockIdx.x * blockDim.x + threadIdx.x;
  if (i >= ntok * 100) return;
  int t = i / 100;
  int d = i - t * 100;
  out[i] = embed[(size_t)idx[t] * 100 + d];
}

// ---------------- weight transpose: in [N,K] -> out [K,N] ----------------
__global__ void transpose_w(const float* __restrict__ in, float* __restrict__ outp, int N, int K) {
  int i = blockIdx.x * blockDim.x + threadIdx.x;
  if (i >= N * K) return;
  int k = i / N;
  int n = i - k * N;
  outp[i] = in[(size_t)n * K + k];
}

// ---------------- generic tiled GEMM: C[M,N] = A[M,K] @ W[N,K]^T (+bias) ----------------
template <typename TA, typename TC, bool HAS_BIAS>
__global__ __launch_bounds__(256) void gemm_tn(
    const TA* __restrict__ A, const float* __restrict__ W,
    const float* __restrict__ bias, TC* __restrict__ C,
    int M, int N, int K) {
  __shared__ float As[16][64];
  __shared__ float Ws[16][64];
  const int m0 = blockIdx.x * 64;
  const int n0 = blockIdx.y * 64;
  const int tid = threadIdx.x;
  const int tx = tid & 15, ty = tid >> 4;
  const int r = tid & 63, cs = (tid >> 6) << 2;
  float acc[4][4] = {};
  for (int k0 = 0; k0 < K; k0 += 16) {
#pragma unroll
    for (int j = 0; j < 4; ++j) {
      int k = k0 + cs + j;
      As[cs + j][r] = (k < K) ? to_f32(A[(size_t)(m0 + r) * K + k]) : 0.f;
      int n = n0 + r;
      Ws[cs + j][r] = (k < K && n < N) ? W[(size_t)n * K + k] : 0.f;
    }
    __syncthreads();
#pragma unroll
    for (int kk = 0; kk < 16; ++kk) {
      float4 a4 = *(const float4*)(&As[kk][ty << 2]);
      float4 b4 = *(const float4*)(&Ws[kk][tx << 2]);
      float a[4] = {a4.x, a4.y, a4.z, a4.w};
      float b[4] = {b4.x, b4.y, b4.z, b4.w};
#pragma unroll
      for (int i = 0; i < 4; ++i)
#pragma unroll
        for (int j = 0; j < 4; ++j) acc[i][j] += a[i] * b[j];
    }
    __syncthreads();
  }
#pragma unroll
  for (int i = 0; i < 4; ++i) {
    int m = m0 + (ty << 2) + i;
#pragma unroll
    for (int j = 0; j < 4; ++j) {
      int n = n0 + (tx << 2) + j;
      if (n < N) {
        float v = acc[i][j];
        if (HAS_BIAS) v += bias[n];
        store_c(&C[(size_t)m * N + n], v);
      }
    }
  }
}

// ---------------- GRU scan, H=100 (ctx / mod0 / mod1), one WG per (batch,dir) ----------------
__global__ __launch_bounds__(320) void gru_scan100(
    const bf16* __restrict__ xw_f, const bf16* __restrict__ xw_b,
    const float* __restrict__ whT,  // [2][100][300]
    const float* __restrict__ bh,   // [2][300]
    float* __restrict__ out,        // [B,T,200]
    int T) {
  const int b = blockIdx.x, dir = blockIdx.y;
  const bf16* xw = dir ? xw_b : xw_f;
  const float* whTd = whT + (size_t)dir * 100 * 300;
  __shared__ float h_s[100];
  __shared__ float g_s[300];
  const int tid = threadIdx.x;
  if (tid < 100) h_s[tid] = 0.f;
  float bhj = (tid < 300) ? bh[dir * 300 + tid] : 0.f;
  __syncthreads();
  for (int step = 0; step < T; ++step) {
    int t = dir ? (T - 1 - step) : step;
    if (tid < 300) {
      float g = bhj;
#pragma unroll 10
      for (int k = 0; k < 100; ++k) g += whTd[k * 300 + tid] * h_s[k];
      g_s[tid] = g;
    }
    __syncthreads();
    if (tid < 100) {
      size_t base = ((size_t)b * T + t) * 300;
      float xr = to_f32(xw[base + tid]);
      float xz = to_f32(xw[base + 100 + tid]);
      float xn = to_f32(xw[base + 200 + tid]);
      float rr = sigmf(xr + g_s[tid]);
      float zz = sigmf(xz + g_s[100 + tid]);
      float nn = tanhf(xn + rr * g_s[200 + tid]);
      float hn = (1.f - zz) * nn + zz * h_s[tid];
      h_s[tid] = hn;
      out[((size_t)b * T + t) * 200 + dir * 100 + tid] = hn;
    }
    __syncthreads();
  }
}

// ---------------- encoder GRU scan, H=400, one WG per batch ----------------
__global__ __launch_bounds__(320) void gru_scan_enc(
    const bf16* __restrict__ xw,    // [B,T,1200]
    const float* __restrict__ whT,  // [400][1200]
    const float* __restrict__ bh,   // [1200]
    float* __restrict__ out,        // [B,T,400]
    int T) {
  const int b = blockIdx.x;
  __shared__ float h_s[400];
  __shared__ float g_s[1200];
  const int tid = threadIdx.x;
  for (int i = tid; i < 400; i += 320) h_s[i] = 0.f;
  float bh0 = 0.f, bh1 = 0.f, bh2 = 0.f, bh3 = 0.f;
  if (tid < 300) {
    bh0 = bh[tid * 4 + 0]; bh1 = bh[tid * 4 + 1];
    bh2 = bh[tid * 4 + 2]; bh3 = bh[tid * 4 + 3];
  }
  __syncthreads();
  for (int step = 0; step < T; ++step) {
    if (tid < 300) {
      float a0 = bh0, a1 = bh1, a2 = bh2, a3 = bh3;
#pragma unroll 2
      for (int k4 = 0; k4 < 100; ++k4) {
        float4 h4 = *(const float4*)(&h_s[k4 * 4]);
        float hk[4] = {h4.x, h4.y, h4.z, h4.w};
#pragma unroll
        for (int u = 0; u < 4; ++u) {
          float4 w = *(const float4*)(&whT[(size_t)(k4 * 4 + u) * 1200 + (tid << 2)]);
          a0 += w.x * hk[u]; a1 += w.y * hk[u]; a2 += w.z * hk[u]; a3 += w.w * hk[u];
        }
      }
      g_s[tid * 4 + 0] = a0; g_s[tid * 4 + 1] = a1;
      g_s[tid * 4 + 2] = a2; g_s[tid * 4 + 3] = a3;
    }
    __syncthreads();
    size_t base = ((size_t)b * T + step) * 1200;
    size_t obase = ((size_t)b * T + step) * 400;
    for (int i = tid; i < 400; i += 320) {
      float xr = to_f32(xw[base + i]);
      float xz = to_f32(xw[base + 400 + i]);
      float xn = to_f32(xw[base + 800 + i]);
      float rr = sigmf(xr + g_s[i]);
      float zz = sigmf(xz + g_s[400 + i]);
      float nn = tanhf(xn + rr * g_s[800 + i]);
      float hn = (1.f - zz) * nn + zz * h_s[i];
      h_s[i] = hn;
      out[obase + i] = hn;
    }
    __syncthreads();
  }
}

// ---------------- row · w (200-dim) -> scalar; one wave per row ----------------
__global__ __launch_bounds__(64) void rowdot200(const float* __restrict__ X, const float* __restrict__ w,
                                                float* __restrict__ out, int rows) {
  int r = blockIdx.x;
  int lane = threadIdx.x;
  const float* x = X + (size_t)r * 200;
  float s = x[lane] * w[lane] + x[lane + 64] * w[lane + 64] + x[lane + 128] * w[lane + 128];
  if (lane < 8) s += x[lane + 192] * w[lane + 192];
  for (int off = 32; off; off >>= 1) s += __shfl_down(s, off);
  if (lane == 0) out[r] = s;
}

// ---------------- attention: S row softmax -> c2q, row max -> smax ----------------
__global__ __launch_bounds__(256) void attn_main(
    const float* __restrict__ h,      // [B,T,200]
    const float* __restrict__ u,      // [B,64,200]
    const float* __restrict__ th,     // [B,T]
    const float* __restrict__ tu,     // [B,64]
    const float* __restrict__ w_sim,  // w3s at +400
    float* __restrict__ c2q,          // [B,T,200]
    float* __restrict__ smax,         // [B,T]
    int T) {
  const int b = blockIdx.x;
  const int t0 = blockIdx.y * 32;
  __shared__ float u_s[64 * 201];
  __shared__ float tu_s[64];
  __shared__ float w3_s[200];
  __shared__ float hw3_s[200];
  __shared__ float Sp[4][64];
  __shared__ float A_s[64];
  const int tid = threadIdx.x;
  for (int i = tid; i < 64 * 200; i += 256) {
    int l = i / 200, d = i - l * 200;
    u_s[l * 201 + d] = u[((size_t)b * 64 + l) * 200 + d];
  }
  if (tid < 64) tu_s[tid] = tu[b * 64 + tid];
  if (tid < 200) w3_s[tid] = w_sim[400 + tid];
  __syncthreads();
  for (int tt = 0; tt < 32; ++tt) {
    int t = t0 + tt;
    if (tid < 200) hw3_s[tid] = h[((size_t)b * T + t) * 200 + tid] * w3_s[tid];
    __syncthreads();
    int l = tid & 63, q = tid >> 6;
    float p = 0.f;
    for (int d = q * 50; d < q * 50 + 50; ++d) p += hw3_s[d] * u_s[l * 201 + d];
    Sp[q][l] = p;
    __syncthreads();
    if (tid < 64) {
      float s = th[b * T + t] + tu_s[l] + Sp[0][l] + Sp[1][l] + Sp[2][l] + Sp[3][l];
      float m = s;
      for (int off = 32; off; off >>= 1) m = fmaxf(m, __shfl_xor(m, off));
      float e = __expf(s - m);
      float ssum = e;
      for (int off = 32; off; off >>= 1) ssum += __shfl_xor(ssum, off);
      A_s[l] = e / ssum;
      if (l == 0) smax[b * T + t] = m;
    }
    __syncthreads();
    if (tid < 200) {
      float acc = 0.f;
      for (int l2 = 0; l2 < 64; ++l2) acc += A_s[l2] * u_s[l2 * 201 + tid];
      c2q[((size_t)b * T + t) * 200 + tid] = acc;
    }
    __syncthreads();
  }
}

// ---------------- softmax over T (per batch row) ----------------
__global__ __launch_bounds__(256) void softmax_T(const float* __restrict__ in, float* __restrict__ outv, int T) {
  int b = blockIdx.x;
  int tid = threadIdx.x;
  __shared__ float red[256];
  float m = -1e30f;
  for (int t = tid; t < T; t += 256) m = fmaxf(m, in[b * T + t]);
  red[tid] = m;
  __syncthreads();
  for (int s = 128; s; s >>= 1) {
    if (tid < s) red[tid] = fmaxf(red[tid], red[tid + s]);
    __syncthreads();
  }
  m = red[0];
  __syncthreads();
  float sum = 0.f;
  for (int t = tid; t < T; t += 256) sum += __expf(in[b * T + t] - m);
  red[tid] = sum;
  __syncthreads();
  for (int s = 128; s; s >>= 1) {
    if (tid < s) red[tid] += red[tid + s];
    __syncthreads();
  }
  float inv = 1.f / red[0];
  for (int t = tid; t < T; t += 256) outv[b * T + t] = __expf(in[b * T + t] - m) * inv;
}

// ---------------- q2c[b,d] = sum_t batt[b,t] * h[b,t,d] ----------------
__global__ __launch_bounds__(256) void q2c_kernel(const float* __restrict__ batt, const float* __restrict__ h,
                                                  float* __restrict__ q2c, int T) {
  int b = blockIdx.x;
  int tid = threadIdx.x;
  if (tid < 200) {
    float acc = 0.f;
    for (int t = 0; t < T; ++t) acc += batt[b * T + t] * h[((size_t)b * T + t) * 200 + tid];
    q2c[b * 200 + tid] = acc;
  }
}

// ---------------- G = [h, c2q, h*c2q, h*q2c] (bf16) ----------------
__global__ void build_G(const float* __restrict__ h, const float* __restrict__ c2q,
                        const float* __restrict__ q2c, bf16* __restrict__ G, int T) {
  size_t i = (size_t)blockIdx.x * blockDim.x + threadIdx.x;
  if (i >= (size_t)32 * T * 200) return;
  size_t row = i / 200;
  int d = (int)(i - row * 200);
  int b = (int)(row / T);
  float hv = h[i];
  float cv = c2q[i];
  float qv = q2c[b * 200 + d];
  bf16* g = G + row * 800;
  g[d] = __float2bfloat16(hv);
  g[200 + d] = __float2bfloat16(cv);
  g[400 + d] = __float2bfloat16(hv * cv);
  g[600 + d] = __float2bfloat16(hv * qv);
}

// ---------------- decoder (batch-uniform since dec_in == 0): d2[2][200] ----------------
__global__ __launch_bounds__(512) void decoder_small(
    const float* __restrict__ dwh,  // [1200,400]
    const float* __restrict__ dbi, const float* __restrict__ dbh,
    const float* __restrict__ w2,  // [200,400]
    float* __restrict__ d2out) {   // [2][200]
  __shared__ float hid[400];
  __shared__ float hid2[400];
  __shared__ float gh[1200];
  const int tid = threadIdx.x;
  if (tid < 400) {
    float r = sigmf(dbi[tid] + dbh[tid]);
    float z = sigmf(dbi[400 + tid] + dbh[400 + tid]);
    float n = tanhf(dbi[800 + tid] + r * dbh[800 + tid]);
    hid[tid] = (1.f - z) * n;
  }
  __syncthreads();
  if (tid < 200) {
    float a = 0.f;
    for (int k = 0; k < 400; ++k) a += w2[(size_t)tid * 400 + k] * hid[k];
    d2out[tid] = a;
  }
  for (int j = tid; j < 1200; j += 512) {
    float a = dbh[j];
    for (int k = 0; k < 400; ++k) a += dwh[(size_t)j * 400 + k] * hid[k];
    gh[j] = a;
  }
  __syncthreads();
  if (tid < 400) {
    float r = sigmf(dbi[tid] + gh[tid]);
    float z = sigmf(dbi[400 + tid] + gh[400 + tid]);
    float n = tanhf(dbi[800 + tid] + r * gh[800 + tid]);
    hid2[tid] = (1.f - z) * n + z * hid[tid];
  }
  __syncthreads();
  if (tid < 200) {
    float a = 0.f;
    for (int k = 0; k < 400; ++k) a += w2[(size_t)tid * 400 + k] * hid2[k];
    d2out[200 + tid] = a;
  }
}

// ---------------- logits: out[b,it,t] = sum_p tanh(encw1[b,t,p]+d2[it][p])*vt[p] ----------------
__global__ __launch_bounds__(64) void logits_kernel(
    const float* __restrict__ encw1,  // [B,T,200]
    const float* __restrict__ d2,     // [2][200]
    const float* __restrict__ vt,     // [200]
    float* __restrict__ outp,         // [B,2,T]
    int T) {
  int row = blockIdx.x;  // b*T + t
  int b = row / T, t = row - b * T;
  int lane = threadIdx.x;
  const float* e = encw1 + (size_t)row * 200;
  float s0 = 0.f, s1 = 0.f;
  for (int p = lane; p < 200; p += 64) {
    float ev = e[p], v = vt[p];
    s0 += tanhf(ev + d2[p]) * v;
    s1 += tanhf(ev + d2[200 + p]) * v;
  }
  for (int off = 32; off; off >>= 1) {
    s0 += __shfl_down(s0, off);
    s1 += __shfl_down(s1, off);
  }
  if (lane == 0) {
    outp[((size_t)b * 2 + 0) * T + t] = s0;
    outp[((size_t)b * 2 + 1) * T + t] = s1;
  }
}

// ---------------- log_softmax over T, in-place ----------------
__global__ __launch_bounds__(256) void log_softmax_T(float* __restrict__ x, int T) {
  int row = blockIdx.x;
  float* p = x + (size_t)row * T;
  __shared__ float red[256];
  int tid = threadIdx.x;
  float m = -1e30f;
  for (int t = tid; t < T; t += 256) m = fmaxf(m, p[t]);
  red[tid] = m;
  __syncthreads();
  for (int s = 128; s; s >>= 1) {
    if (tid < s) red[tid] = fmaxf(red[tid], red[tid + s]);
    __syncthreads();
  }
  m = red[0];
  __syncthreads();
  float sum = 0.f;
  for (int t = tid; t < T; t += 256) sum += __expf(p[t] - m);
  red[tid] = sum;
  __syncthreads();
  for (int s = 128; s; s >>= 1) {
    if (tid < s) red[tid] += red[tid + s];
    __syncthreads();
  }
  float lse = m + __logf(red[0]);
  __syncthreads();
  for (int t = tid; t < T; t += 256) p[t] = p[t] - lse;
}

extern "C" void kernel_launch(void* const* d_in, const int* in_sizes, int n_in,
                              void* d_out, int out_size, void* d_ws, size_t ws_size,
                              hipStream_t stream) {
  (void)in_sizes; (void)n_in; (void)out_size; (void)ws_size;
  const int B = 32, T = 512, L = 64;
  const int BT = B * T;    // 16384
  const int BL = B * L;    // 2048

  const int* x_word = (const int*)d_in[0];
  const int* x_query = (const int*)d_in[1];
  const float* embed = (const float*)d_in[2];
  const float* ctx_wi = (const float*)d_in[3];
  const float* ctx_wh = (const float*)d_in[4];
  const float* ctx_bi = (const float*)d_in[5];
  const float* ctx_bh = (const float*)d_in[6];
  const float* mod0_wi = (const float*)d_in[7];
  const float* mod0_wh = (const float*)d_in[8];
  const float* mod0_bi = (const float*)d_in[9];
  const float* mod0_bh = (const float*)d_in[10];
  const float* mod1_wi = (const float*)d_in[11];
  const float* mod1_wh = (const float*)d_in[12];
  const float* mod1_bi = (const float*)d_in[13];
  const float* mod1_bh = (const float*)d_in[14];
  const float* w_sim = (const float*)d_in[15];
  const float* enc_wi = (const float*)d_in[16];
  const float* enc_wh = (const float*)d_in[17];
  const float* enc_bi = (const float*)d_in[18];
  const float* enc_bh = (const float*)d_in[19];
  const float* dec_wh = (const float*)d_in[21];
  const float* dec_bi = (const float*)d_in[22];
  const float* dec_bh = (const float*)d_in[23];
  const float* w1 = (const float*)d_in[24];
  const float* w2 = (const float*)d_in[25];
  const float* vt = (const float*)d_in[26];
  float* out_f = (float*)d_out;

  // ---- workspace layout (region reuse; ~107 MB total) ----
  char* ws = (char*)d_ws;
  size_t off = 0;
  auto alloc = [&](size_t bytes) -> void* {
    void* p = ws + off;
    off += (bytes + 255) & ~(size_t)255;
    return p;
  };
  float* whT_ctx = (float*)alloc((size_t)2 * 30000 * 4);
  float* whT_m0 = (float*)alloc((size_t)2 * 30000 * 4);
  float* whT_m1 = (float*)alloc((size_t)2 * 30000 * 4);
  float* whT_enc = (float*)alloc((size_t)480000 * 4);
  float* ew = (float*)alloc((size_t)BT * 100 * 4);
  float* eq = (float*)alloc((size_t)BL * 100 * 4);
  char* RA = (char*)alloc((size_t)BT * 1200 * 2);  // 39.3 MB
  bf16* xwA = (bf16*)RA;                            // [BT,300] bf16
  bf16* xwB = (bf16*)(RA + (size_t)BT * 300 * 2);
  bf16* xwe = (bf16*)RA;                            // [BT,1200] bf16 (later)
  bf16* xwqF = (bf16*)alloc((size_t)BL * 300 * 2);
  bf16* xwqB = (bf16*)alloc((size_t)BL * 300 * 2);
  char* RB = (char*)alloc((size_t)BT * 800 * 2);   // 26.2 MB
  bf16* G = (bf16*)RB;
  float* enc_out = (float*)RB;                      // [BT,400] f32 (later, same size)
  char* RC = (char*)alloc((size_t)2 * BT * 200 * 4);  // 26.2 MB
  float* h_cat = (float*)RC;                        // [BT,200]
  float* c2q = (float*)(RC + (size_t)BT * 200 * 4);
  float* M0 = c2q;                                  // reuse (c2q dead after G)
  float* Mx = h_cat;                                // reuse (h dead after G)
  float* encw1 = c2q;                               // reuse (M0 dead after xw1)
  float* u_cat = (float*)alloc((size_t)BL * 200 * 4);
  float* th = (float*)alloc((size_t)BT * 4);
  float* tu = (float*)alloc((size_t)BL * 4);
  float* smaxb = (float*)alloc((size_t)BT * 4);
  float* batt = (float*)alloc((size_t)BT * 4);
  float* q2cb = (float*)alloc((size_t)B * 200 * 4);
  float* d2 = (float*)alloc((size_t)400 * 4);

  // ---- 1. weight transposes ----
  transpose_w<<<(30000 + 255) / 256, 256, 0, stream>>>(ctx_wh, whT_ctx, 300, 100);
  transpose_w<<<(30000 + 255) / 256, 256, 0, stream>>>(ctx_wh + 30000, whT_ctx + 30000, 300, 100);
  transpose_w<<<(30000 + 255) / 256, 256, 0, stream>>>(mod0_wh, whT_m0, 300, 100);
  transpose_w<<<(30000 + 255) / 256, 256, 0, stream>>>(mod0_wh + 30000, whT_m0 + 30000, 300, 100);
  transpose_w<<<(30000 + 255) / 256, 256, 0, stream>>>(mod1_wh, whT_m1, 300, 100);
  transpose_w<<<(30000 + 255) / 256, 256, 0, stream>>>(mod1_wh + 30000, whT_m1 + 30000, 300, 100);
  transpose_w<<<(480000 + 255) / 256, 256, 0, stream>>>(enc_wh, whT_enc, 1200, 400);

  // ---- 2. embedding gathers ----
  gather_embed<<<(BT * 100 + 255) / 256, 256, 0, stream>>>(x_word, embed, ew, BT);
  gather_embed<<<(BL * 100 + 255) / 256, 256, 0, stream>>>(x_query, embed, eq, BL);

  // ---- 3. ctx input projections ----
  {
    dim3 g(BT / 64, (300 + 63) / 64);
    gemm_tn<float, bf16, true><<<g, 256, 0, stream>>>(ew, ctx_wi, ctx_bi, xwA, BT, 300, 100);
    gemm_tn<float, bf16, true><<<g, 256, 0, stream>>>(ew, ctx_wi + 30000, ctx_bi + 300, xwB, BT, 300, 100);
    dim3 gq(BL / 64, (300 + 63) / 64);
    gemm_tn<float, bf16, true><<<gq, 256, 0, stream>>>(eq, ctx_wi, ctx_bi, xwqF, BL, 300, 100);
    gemm_tn<float, bf16, true><<<gq, 256, 0, stream>>>(eq, ctx_wi + 30000, ctx_bi + 300, xwqB, BL, 300, 100);
  }

  // ---- 4. ctx scans ----
  gru_scan100<<<dim3(B, 2), 320, 0, stream>>>(xwA, xwB, whT_ctx, ctx_bh, h_cat, T);
  gru_scan100<<<dim3(B, 2), 320, 0, stream>>>(xwqF, xwqB, whT_ctx, ctx_bh, u_cat, L);

  // ---- 5. attention ----
  rowdot200<<<BT, 64, 0, stream>>>(h_cat, w_sim, th, BT);
  rowdot200<<<BL, 64, 0, stream>>>(u_cat, w_sim + 200, tu, BL);
  attn_main<<<dim3(B, T / 32), 256, 0, stream>>>(h_cat, u_cat, th, tu, w_sim, c2q, smaxb, T);
  softmax_T<<<B, 256, 0, stream>>>(smaxb, batt, T);
  q2c_kernel<<<B, 256, 0, stream>>>(batt, h_cat, q2cb, T);
  build_G<<<(BT * 200 + 255) / 256, 256, 0, stream>>>(h_cat, c2q, q2cb, G, T);

  // ---- 6. mod0 ----
  {
    dim3 g(BT / 64, (300 + 63) / 64);
    gemm_tn<bf16, bf16, true><<<g, 256, 0, stream>>>(G, mod0_wi, mod0_bi, xwA, BT, 300, 800);
    gemm_tn<bf16, bf16, true><<<g, 256, 0, stream>>>(G, mod0_wi + 240000, mod0_bi + 300, xwB, BT, 300, 800);
  }
  gru_scan100<<<dim3(B, 2), 320, 0, stream>>>(xwA, xwB, whT_m0, mod0_bh, M0, T);

  // ---- 7. mod1 ----
  {
    dim3 g(BT / 64, (300 + 63) / 64);
    gemm_tn<float, bf16, true><<<g, 256, 0, stream>>>(M0, mod1_wi, mod1_bi, xwA, BT, 300, 200);
    gemm_tn<float, bf16, true><<<g, 256, 0, stream>>>(M0, mod1_wi + 60000, mod1_bi + 300, xwB, BT, 300, 200);
  }
  gru_scan100<<<dim3(B, 2), 320, 0, stream>>>(xwA, xwB, whT_m1, mod1_bh, Mx, T);

  // ---- 8. encoder ----
  {
    dim3 g(BT / 64, (1200 + 63) / 64);
    gemm_tn<float, bf16, true><<<g, 256, 0, stream>>>(Mx, enc_wi, enc_bi, xwe, BT, 1200, 200);
  }
  gru_scan_enc<<<B, 320, 0, stream>>>(xwe, whT_enc, enc_bh, enc_out, T);
  {
    dim3 g(BT / 64, (200 + 63) / 64);
    gemm_tn<float, float, false><<<g, 256, 0, stream>>>(enc_out, w1, nullptr, encw1, BT, 200, 400);
  }

  // ---- 9. pointer decoder ----
  decoder_small<<<1, 512, 0, stream>>>(dec_wh, dec_bi, dec_bh, w2, d2);
  logits_kernel<<<BT, 64, 0, stream>>>(encw1, d2, vt, out_f, T);
  log_softmax_T<<<B * 2, 256, 0, stream>>>(out_f, T);
}

// Round 2
// 6557.742 us; speedup vs baseline: 1.8804x; 1.8804x over previous
//
#include <hip/hip_runtime.h>
#include <hip/hip_bf16.h>

typedef __hip_bfloat16 bf16;

#define DEV __device__ __forceinline__

DEV float to_f32(float x) { return x; }
DEV float to_f32(bf16 x) { return __bfloat162float(x); }
DEV void store_c(float* p, float v) { *p = v; }
DEV void store_c(bf16* p, float v) { *p = __float2bfloat16(v); }
DEV float sigmf(float x) { return 1.f / (1.f + __expf(-x)); }

// ---------------- embedding gather ----------------
__global__ void gather_embed(const int* __restrict__ idx, const float* __restrict__ embed,
                             float* __restrict__ out, int ntok) {
  int i = blockIdx.x * blockDim.x + threadIdx.x;
  if (i >= ntok * 100) return;
  int t = i / 100;
  int d = i - t * 100;
  out[i] = embed[(size_t)idx[t] * 100 + d];
}

// ---------------- generic tiled GEMM: C[M,N] = A[M,K] @ W[N,K]^T (+bias) ----------------
template <typename TA, typename TC, bool HAS_BIAS>
__global__ __launch_bounds__(256) void gemm_tn(
    const TA* __restrict__ A, const float* __restrict__ W,
    const float* __restrict__ bias, TC* __restrict__ C,
    int M, int N, int K) {
  __shared__ float As[16][64];
  __shared__ float Ws[16][64];
  const int m0 = blockIdx.x * 64;
  const int n0 = blockIdx.y * 64;
  const int tid = threadIdx.x;
  const int tx = tid & 15, ty = tid >> 4;
  const int r = tid & 63, cs = (tid >> 6) << 2;
  float acc[4][4] = {};
  for (int k0 = 0; k0 < K; k0 += 16) {
#pragma unroll
    for (int j = 0; j < 4; ++j) {
      int k = k0 + cs + j;
      As[cs + j][r] = (k < K) ? to_f32(A[(size_t)(m0 + r) * K + k]) : 0.f;
      int n = n0 + r;
      Ws[cs + j][r] = (k < K && n < N) ? W[(size_t)n * K + k] : 0.f;
    }
    __syncthreads();
#pragma unroll
    for (int kk = 0; kk < 16; ++kk) {
      float4 a4 = *(const float4*)(&As[kk][ty << 2]);
      float4 b4 = *(const float4*)(&Ws[kk][tx << 2]);
      float a[4] = {a4.x, a4.y, a4.z, a4.w};
      float b[4] = {b4.x, b4.y, b4.z, b4.w};
#pragma unroll
      for (int i = 0; i < 4; ++i)
#pragma unroll
        for (int j = 0; j < 4; ++j) acc[i][j] += a[i] * b[j];
    }
    __syncthreads();
  }
#pragma unroll
  for (int i = 0; i < 4; ++i) {
    int m = m0 + (ty << 2) + i;
#pragma unroll
    for (int j = 0; j < 4; ++j) {
      int n = n0 + (tx << 2) + j;
      if (n < N) {
        float v = acc[i][j];
        if (HAS_BIAS) v += bias[n];
        store_c(&C[(size_t)m * N + n], v);
      }
    }
  }
}

// ---------------- GRU scan H=100, register-resident weights, one WG per (batch,dir) ----------------
__global__ __launch_bounds__(320) void gru_scan100_reg(
    const bf16* __restrict__ xw_f, const bf16* __restrict__ xw_b,
    const float* __restrict__ wh,  // [2][300][100] (raw layout)
    const float* __restrict__ bh,  // [2][300]
    float* __restrict__ out,       // [B,T,200]
    int T) {
  const int b = blockIdx.x, dir = blockIdx.y;
  const bf16* xw = dir ? xw_b : xw_f;
  __shared__ float h_s[100];
  __shared__ float g_s[300];
  const int tid = threadIdx.x;
  float w[100];
  float bias = 0.f;
  if (tid < 300) {
    const float* wrow = wh + (size_t)dir * 30000 + (size_t)tid * 100;
#pragma unroll
    for (int c = 0; c < 25; ++c) {
      float4 v = *(const float4*)(wrow + 4 * c);
      w[4 * c] = v.x; w[4 * c + 1] = v.y; w[4 * c + 2] = v.z; w[4 * c + 3] = v.w;
    }
    bias = bh[dir * 300 + tid];
  }
  if (tid < 100) h_s[tid] = 0.f;
  __syncthreads();
  for (int step = 0; step < T; ++step) {
    int t = dir ? (T - 1 - step) : step;
    if (tid < 300) {
      float a0 = bias, a1 = 0.f, a2 = 0.f, a3 = 0.f;
#pragma unroll
      for (int c = 0; c < 25; ++c) {
        float4 h4 = *(const float4*)(&h_s[4 * c]);
        a0 += w[4 * c] * h4.x; a1 += w[4 * c + 1] * h4.y;
        a2 += w[4 * c + 2] * h4.z; a3 += w[4 * c + 3] * h4.w;
      }
      g_s[tid] = (a0 + a1) + (a2 + a3);
    }
    __syncthreads();
    if (tid < 100) {
      size_t base = ((size_t)b * T + t) * 300;
      float xr = to_f32(xw[base + tid]);
      float xz = to_f32(xw[base + 100 + tid]);
      float xn = to_f32(xw[base + 200 + tid]);
      float rr = sigmf(xr + g_s[tid]);
      float zz = sigmf(xz + g_s[100 + tid]);
      float nn = tanhf(xn + rr * g_s[200 + tid]);
      float hn = (1.f - zz) * nn + zz * h_s[tid];
      h_s[tid] = hn;
      out[((size_t)b * T + t) * 200 + dir * 100 + tid] = hn;
    }
    __syncthreads();
  }
}

// ---------------- encoder GRU scan H=400: 8 WGs per batch, register weights, flag sync --------
// grid dim3(32,8): b=blockIdx.x, s=blockIdx.y -> linear id = b + 32*s, so all 8 slices of a
// batch share (b mod 8) -> same XCD under round-robin dispatch (perf heuristic only).
__global__ __launch_bounds__(320) void gru_scan_enc_mw(
    const bf16* __restrict__ xw,   // [B,T,1200]
    const float* __restrict__ wh,  // [1200,400] raw
    const float* __restrict__ bh,  // [1200]
    float* __restrict__ out,       // [B,T,400]
    float* __restrict__ h_all,     // [B,400]   (pre-zeroed)
    int* __restrict__ flags,       // [B,8]     (pre-zeroed)
    int T) {
  const int b = blockIdx.x, s = blockIdx.y;
  __shared__ float h_s[400];
  __shared__ float g_s[150];
  const int tid = threadIdx.x;
  const int g = tid >> 1, p = tid & 1;  // gate g in [0,150), k-half p
  float w[200];
  float bias = 0.f;
  if (tid < 300) {
    int i = g % 50, grp = g / 50;  // grp: 0=r 1=z 2=n
    int gidx = grp * 400 + s * 50 + i;
    const float* wrow = wh + (size_t)gidx * 400 + p * 200;
#pragma unroll
    for (int c = 0; c < 50; ++c) {
      float4 v = *(const float4*)(wrow + 4 * c);
      w[4 * c] = v.x; w[4 * c + 1] = v.y; w[4 * c + 2] = v.z; w[4 * c + 3] = v.w;
    }
    if (p == 0) bias = bh[gidx];
  }
  for (int k = tid; k < 400; k += 320) h_s[k] = 0.f;
  __syncthreads();
  for (int t = 0; t < T; ++t) {
    // gate dot products: slice of 150 gates, k split over p
    if (tid < 300) {
      float a0 = bias, a1 = 0.f, a2 = 0.f, a3 = 0.f;
      const int hb = p * 200;
#pragma unroll
      for (int c = 0; c < 50; ++c) {
        float4 h4 = *(const float4*)(&h_s[hb + 4 * c]);
        a0 += w[4 * c] * h4.x; a1 += w[4 * c + 1] * h4.y;
        a2 += w[4 * c + 2] * h4.z; a3 += w[4 * c + 3] * h4.w;
      }
      float acc = (a0 + a1) + (a2 + a3);
      acc += __shfl_xor(acc, 1);  // combine the two k-halves (adjacent lanes)
      if (p == 0) g_s[g] = acc;
    }
    __syncthreads();
    // slice-local h update (own 50 elements)
    if (tid < 50) {
      size_t base = ((size_t)b * T + t) * 1200;
      int i = s * 50 + tid;
      float xr = to_f32(xw[base + i]);
      float xz = to_f32(xw[base + 400 + i]);
      float xn = to_f32(xw[base + 800 + i]);
      float rr = sigmf(xr + g_s[tid]);
      float zz = sigmf(xz + g_s[50 + tid]);
      float nn = tanhf(xn + rr * g_s[100 + tid]);
      float hn = (1.f - zz) * nn + zz * h_s[i];
      out[((size_t)b * T + t) * 400 + i] = hn;
      __hip_atomic_store(&h_all[b * 400 + i], hn, __ATOMIC_RELAXED, __HIP_MEMORY_SCOPE_AGENT);
    }
    // __syncthreads drains each wave's vmcnt -> all 50 agent-scope stores are at the
    // coherence point before the flag store below is issued.
    __syncthreads();
    if (tid == 0)
      __hip_atomic_store(&flags[b * 8 + s], t + 1, __ATOMIC_RELEASE, __HIP_MEMORY_SCOPE_AGENT);
    if (tid < 8) {
      while (__hip_atomic_load(&flags[b * 8 + tid], __ATOMIC_ACQUIRE, __HIP_MEMORY_SCOPE_AGENT) < t + 1)
        __builtin_amdgcn_s_sleep(4);
    }
    __syncthreads();
    for (int k = tid; k < 400; k += 320)
      h_s[k] = __hip_atomic_load(&h_all[b * 400 + k], __ATOMIC_RELAXED, __HIP_MEMORY_SCOPE_AGENT);
    __syncthreads();
  }
}

// ---------------- row · w (200-dim) -> scalar; one wave per row ----------------
__global__ __launch_bounds__(64) void rowdot200(const float* __restrict__ X, const float* __restrict__ w,
                                                float* __restrict__ out, int rows) {
  int r = blockIdx.x;
  int lane = threadIdx.x;
  const float* x = X + (size_t)r * 200;
  float s = x[lane] * w[lane] + x[lane + 64] * w[lane + 64] + x[lane + 128] * w[lane + 128];
  if (lane < 8) s += x[lane + 192] * w[lane + 192];
  for (int off = 32; off; off >>= 1) s += __shfl_down(s, off);
  if (lane == 0) out[r] = s;
}

// ---------------- attention: S row softmax -> c2q, row max -> smax ----------------
__global__ __launch_bounds__(256) void attn_main(
    const float* __restrict__ h,      // [B,T,200]
    const float* __restrict__ u,      // [B,64,200]
    const float* __restrict__ th,     // [B,T]
    const float* __restrict__ tu,     // [B,64]
    const float* __restrict__ w_sim,  // w3s at +400
    float* __restrict__ c2q,          // [B,T,200]
    float* __restrict__ smax,         // [B,T]
    int T) {
  const int b = blockIdx.x;
  const int t0 = blockIdx.y * 32;
  __shared__ float u_s[64 * 201];
  __shared__ float tu_s[64];
  __shared__ float w3_s[200];
  __shared__ float hw3_s[200];
  __shared__ float Sp[4][64];
  __shared__ float A_s[64];
  const int tid = threadIdx.x;
  for (int i = tid; i < 64 * 200; i += 256) {
    int l = i / 200, d = i - l * 200;
    u_s[l * 201 + d] = u[((size_t)b * 64 + l) * 200 + d];
  }
  if (tid < 64) tu_s[tid] = tu[b * 64 + tid];
  if (tid < 200) w3_s[tid] = w_sim[400 + tid];
  __syncthreads();
  for (int tt = 0; tt < 32; ++tt) {
    int t = t0 + tt;
    if (tid < 200) hw3_s[tid] = h[((size_t)b * T + t) * 200 + tid] * w3_s[tid];
    __syncthreads();
    int l = tid & 63, q = tid >> 6;
    float p = 0.f;
    for (int d = q * 50; d < q * 50 + 50; ++d) p += hw3_s[d] * u_s[l * 201 + d];
    Sp[q][l] = p;
    __syncthreads();
    if (tid < 64) {
      float s = th[b * T + t] + tu_s[l] + Sp[0][l] + Sp[1][l] + Sp[2][l] + Sp[3][l];
      float m = s;
      for (int off = 32; off; off >>= 1) m = fmaxf(m, __shfl_xor(m, off));
      float e = __expf(s - m);
      float ssum = e;
      for (int off = 32; off; off >>= 1) ssum += __shfl_xor(ssum, off);
      A_s[l] = e / ssum;
      if (l == 0) smax[b * T + t] = m;
    }
    __syncthreads();
    if (tid < 200) {
      float acc = 0.f;
      for (int l2 = 0; l2 < 64; ++l2) acc += A_s[l2] * u_s[l2 * 201 + tid];
      c2q[((size_t)b * T + t) * 200 + tid] = acc;
    }
    __syncthreads();
  }
}

// ---------------- softmax over T (per batch row) ----------------
__global__ __launch_bounds__(256) void softmax_T(const float* __restrict__ in, float* __restrict__ outv, int T) {
  int b = blockIdx.x;
  int tid = threadIdx.x;
  __shared__ float red[256];
  float m = -1e30f;
  for (int t = tid; t < T; t += 256) m = fmaxf(m, in[b * T + t]);
  red[tid] = m;
  __syncthreads();
  for (int s = 128; s; s >>= 1) {
    if (tid < s) red[tid] = fmaxf(red[tid], red[tid + s]);
    __syncthreads();
  }
  m = red[0];
  __syncthreads();
  float sum = 0.f;
  for (int t = tid; t < T; t += 256) sum += __expf(in[b * T + t] - m);
  red[tid] = sum;
  __syncthreads();
  for (int s = 128; s; s >>= 1) {
    if (tid < s) red[tid] += red[tid + s];
    __syncthreads();
  }
  float inv = 1.f / red[0];
  for (int t = tid; t < T; t += 256) outv[b * T + t] = __expf(in[b * T + t] - m) * inv;
}

// ---------------- q2c[b,d] = sum_t batt[b,t] * h[b,t,d] ----------------
__global__ __launch_bounds__(256) void q2c_kernel(const float* __restrict__ batt, const float* __restrict__ h,
                                                  float* __restrict__ q2c, int T) {
  int b = blockIdx.x;
  int tid = threadIdx.x;
  if (tid < 200) {
    float acc = 0.f;
    for (int t = 0; t < T; ++t) acc += batt[b * T + t] * h[((size_t)b * T + t) * 200 + tid];
    q2c[b * 200 + tid] = acc;
  }
}

// ---------------- G = [h, c2q, h*c2q, h*q2c] (bf16) ----------------
__global__ void build_G(const float* __restrict__ h, const float* __restrict__ c2q,
                        const float* __restrict__ q2c, bf16* __restrict__ G, int T) {
  size_t i = (size_t)blockIdx.x * blockDim.x + threadIdx.x;
  if (i >= (size_t)32 * T * 200) return;
  size_t row = i / 200;
  int d = (int)(i - row * 200);
  int b = (int)(row / T);
  float hv = h[i];
  float cv = c2q[i];
  float qv = q2c[b * 200 + d];
  bf16* g = G + row * 800;
  g[d] = __float2bfloat16(hv);
  g[200 + d] = __float2bfloat16(cv);
  g[400 + d] = __float2bfloat16(hv * cv);
  g[600 + d] = __float2bfloat16(hv * qv);
}

// ---------------- decoder (batch-uniform since dec_in == 0): d2[2][200] ----------------
__global__ __launch_bounds__(512) void decoder_small(
    const float* __restrict__ dwh,  // [1200,400]
    const float* __restrict__ dbi, const float* __restrict__ dbh,
    const float* __restrict__ w2,  // [200,400]
    float* __restrict__ d2out) {   // [2][200]
  __shared__ float hid[400];
  __shared__ float hid2[400];
  __shared__ float gh[1200];
  const int tid = threadIdx.x;
  if (tid < 400) {
    float r = sigmf(dbi[tid] + dbh[tid]);
    float z = sigmf(dbi[400 + tid] + dbh[400 + tid]);
    float n = tanhf(dbi[800 + tid] + r * dbh[800 + tid]);
    hid[tid] = (1.f - z) * n;
  }
  __syncthreads();
  if (tid < 200) {
    float a = 0.f;
    for (int k = 0; k < 400; ++k) a += w2[(size_t)tid * 400 + k] * hid[k];
    d2out[tid] = a;
  }
  for (int j = tid; j < 1200; j += 512) {
    float a = dbh[j];
    for (int k = 0; k < 400; ++k) a += dwh[(size_t)j * 400 + k] * hid[k];
    gh[j] = a;
  }
  __syncthreads();
  if (tid < 400) {
    float r = sigmf(dbi[tid] + gh[tid]);
    float z = sigmf(dbi[400 + tid] + gh[400 + tid]);
    float n = tanhf(dbi[800 + tid] + r * gh[800 + tid]);
    hid2[tid] = (1.f - z) * n + z * hid[tid];
  }
  __syncthreads();
  if (tid < 200) {
    float a = 0.f;
    for (int k = 0; k < 400; ++k) a += w2[(size_t)tid * 400 + k] * hid2[k];
    d2out[200 + tid] = a;
  }
}

// ---------------- logits: out[b,it,t] = sum_p tanh(encw1[b,t,p]+d2[it][p])*vt[p] ----------------
__global__ __launch_bounds__(64) void logits_kernel(
    const float* __restrict__ encw1,  // [B,T,200]
    const float* __restrict__ d2,     // [2][200]
    const float* __restrict__ vt,     // [200]
    float* __restrict__ outp,         // [B,2,T]
    int T) {
  int row = blockIdx.x;  // b*T + t
  int b = row / T, t = row - b * T;
  int lane = threadIdx.x;
  const float* e = encw1 + (size_t)row * 200;
  float s0 = 0.f, s1 = 0.f;
  for (int p = lane; p < 200; p += 64) {
    float ev = e[p], v = vt[p];
    s0 += tanhf(ev + d2[p]) * v;
    s1 += tanhf(ev + d2[200 + p]) * v;
  }
  for (int off = 32; off; off >>= 1) {
    s0 += __shfl_down(s0, off);
    s1 += __shfl_down(s1, off);
  }
  if (lane == 0) {
    outp[((size_t)b * 2 + 0) * T + t] = s0;
    outp[((size_t)b * 2 + 1) * T + t] = s1;
  }
}

// ---------------- log_softmax over T, in-place ----------------
__global__ __launch_bounds__(256) void log_softmax_T(float* __restrict__ x, int T) {
  int row = blockIdx.x;
  float* p = x + (size_t)row * T;
  __shared__ float red[256];
  int tid = threadIdx.x;
  float m = -1e30f;
  for (int t = tid; t < T; t += 256) m = fmaxf(m, p[t]);
  red[tid] = m;
  __syncthreads();
  for (int s = 128; s; s >>= 1) {
    if (tid < s) red[tid] = fmaxf(red[tid], red[tid + s]);
    __syncthreads();
  }
  m = red[0];
  __syncthreads();
  float sum = 0.f;
  for (int t = tid; t < T; t += 256) sum += __expf(p[t] - m);
  red[tid] = sum;
  __syncthreads();
  for (int s = 128; s; s >>= 1) {
    if (tid < s) red[tid] += red[tid + s];
    __syncthreads();
  }
  float lse = m + __logf(red[0]);
  __syncthreads();
  for (int t = tid; t < T; t += 256) p[t] = p[t] - lse;
}

extern "C" void kernel_launch(void* const* d_in, const int* in_sizes, int n_in,
                              void* d_out, int out_size, void* d_ws, size_t ws_size,
                              hipStream_t stream) {
  (void)in_sizes; (void)n_in; (void)out_size; (void)ws_size;
  const int B = 32, T = 512, L = 64;
  const int BT = B * T;    // 16384
  const int BL = B * L;    // 2048

  const int* x_word = (const int*)d_in[0];
  const int* x_query = (const int*)d_in[1];
  const float* embed = (const float*)d_in[2];
  const float* ctx_wi = (const float*)d_in[3];
  const float* ctx_wh = (const float*)d_in[4];
  const float* ctx_bi = (const float*)d_in[5];
  const float* ctx_bh = (const float*)d_in[6];
  const float* mod0_wi = (const float*)d_in[7];
  const float* mod0_wh = (const float*)d_in[8];
  const float* mod0_bi = (const float*)d_in[9];
  const float* mod0_bh = (const float*)d_in[10];
  const float* mod1_wi = (const float*)d_in[11];
  const float* mod1_wh = (const float*)d_in[12];
  const float* mod1_bi = (const float*)d_in[13];
  const float* mod1_bh = (const float*)d_in[14];
  const float* w_sim = (const float*)d_in[15];
  const float* enc_wi = (const float*)d_in[16];
  const float* enc_wh = (const float*)d_in[17];
  const float* enc_bi = (const float*)d_in[18];
  const float* enc_bh = (const float*)d_in[19];
  const float* dec_wh = (const float*)d_in[21];
  const float* dec_bi = (const float*)d_in[22];
  const float* dec_bh = (const float*)d_in[23];
  const float* w1 = (const float*)d_in[24];
  const float* w2 = (const float*)d_in[25];
  const float* vt = (const float*)d_in[26];
  float* out_f = (float*)d_out;

  // ---- workspace layout (region reuse) ----
  char* ws = (char*)d_ws;
  size_t off = 0;
  auto alloc = [&](size_t bytes) -> void* {
    void* p = ws + off;
    off += (bytes + 255) & ~(size_t)255;
    return p;
  };
  float* h_all = (float*)alloc((size_t)B * 400 * 4);  // 51200 B (contiguous with flags)
  int* flags = (int*)alloc((size_t)B * 8 * 4);        // 1024 B
  float* ew = (float*)alloc((size_t)BT * 100 * 4);
  float* eq = (float*)alloc((size_t)BL * 100 * 4);
  char* RA = (char*)alloc((size_t)BT * 1200 * 2);  // 39.3 MB
  bf16* xwA = (bf16*)RA;                            // [BT,300] bf16
  bf16* xwB = (bf16*)(RA + (size_t)BT * 300 * 2);
  bf16* xwe = (bf16*)RA;                            // [BT,1200] bf16 (later)
  bf16* xwqF = (bf16*)alloc((size_t)BL * 300 * 2);
  bf16* xwqB = (bf16*)alloc((size_t)BL * 300 * 2);
  char* RB = (char*)alloc((size_t)BT * 800 * 2);   // 26.2 MB
  bf16* G = (bf16*)RB;
  float* enc_out = (float*)RB;                      // [BT,400] f32 (later, same size)
  char* RC = (char*)alloc((size_t)2 * BT * 200 * 4);  // 26.2 MB
  float* h_cat = (float*)RC;                        // [BT,200]
  float* c2q = (float*)(RC + (size_t)BT * 200 * 4);
  float* M0 = c2q;                                  // reuse (c2q dead after G)
  float* Mx = h_cat;                                // reuse (h dead after G)
  float* encw1 = c2q;                               // reuse (M0 dead after xw1)
  float* u_cat = (float*)alloc((size_t)BL * 200 * 4);
  float* th = (float*)alloc((size_t)BT * 4);
  float* tu = (float*)alloc((size_t)BL * 4);
  float* smaxb = (float*)alloc((size_t)BT * 4);
  float* batt = (float*)alloc((size_t)BT * 4);
  float* q2cb = (float*)alloc((size_t)B * 200 * 4);
  float* d2 = (float*)alloc((size_t)400 * 4);

  // ---- 0. zero h_all + flags (required fresh every call; flags grow monotonically) ----
  hipMemsetAsync(h_all, 0, (size_t)B * 400 * 4 + 256 /*covers flags (aligned next)*/ + (size_t)B * 8 * 4 - 256, stream);
  hipMemsetAsync(flags, 0, (size_t)B * 8 * 4, stream);

  // ---- 1. embedding gathers ----
  gather_embed<<<(BT * 100 + 255) / 256, 256, 0, stream>>>(x_word, embed, ew, BT);
  gather_embed<<<(BL * 100 + 255) / 256, 256, 0, stream>>>(x_query, embed, eq, BL);

  // ---- 2. ctx input projections ----
  {
    dim3 g(BT / 64, (300 + 63) / 64);
    gemm_tn<float, bf16, true><<<g, 256, 0, stream>>>(ew, ctx_wi, ctx_bi, xwA, BT, 300, 100);
    gemm_tn<float, bf16, true><<<g, 256, 0, stream>>>(ew, ctx_wi + 30000, ctx_bi + 300, xwB, BT, 300, 100);
    dim3 gq(BL / 64, (300 + 63) / 64);
    gemm_tn<float, bf16, true><<<gq, 256, 0, stream>>>(eq, ctx_wi, ctx_bi, xwqF, BL, 300, 100);
    gemm_tn<float, bf16, true><<<gq, 256, 0, stream>>>(eq, ctx_wi + 30000, ctx_bi + 300, xwqB, BL, 300, 100);
  }

  // ---- 3. ctx scans (register-resident weights) ----
  gru_scan100_reg<<<dim3(B, 2), 320, 0, stream>>>(xwA, xwB, ctx_wh, ctx_bh, h_cat, T);
  gru_scan100_reg<<<dim3(B, 2), 320, 0, stream>>>(xwqF, xwqB, ctx_wh, ctx_bh, u_cat, L);

  // ---- 4. attention ----
  rowdot200<<<BT, 64, 0, stream>>>(h_cat, w_sim, th, BT);
  rowdot200<<<BL, 64, 0, stream>>>(u_cat, w_sim + 200, tu, BL);
  attn_main<<<dim3(B, T / 32), 256, 0, stream>>>(h_cat, u_cat, th, tu, w_sim, c2q, smaxb, T);
  softmax_T<<<B, 256, 0, stream>>>(smaxb, batt, T);
  q2c_kernel<<<B, 256, 0, stream>>>(batt, h_cat, q2cb, T);
  build_G<<<(BT * 200 + 255) / 256, 256, 0, stream>>>(h_cat, c2q, q2cb, G, T);

  // ---- 5. mod0 ----
  {
    dim3 g(BT / 64, (300 + 63) / 64);
    gemm_tn<bf16, bf16, true><<<g, 256, 0, stream>>>(G, mod0_wi, mod0_bi, xwA, BT, 300, 800);
    gemm_tn<bf16, bf16, true><<<g, 256, 0, stream>>>(G, mod0_wi + 240000, mod0_bi + 300, xwB, BT, 300, 800);
  }
  gru_scan100_reg<<<dim3(B, 2), 320, 0, stream>>>(xwA, xwB, mod0_wh, mod0_bh, M0, T);

  // ---- 6. mod1 ----
  {
    dim3 g(BT / 64, (300 + 63) / 64);
    gemm_tn<float, bf16, true><<<g, 256, 0, stream>>>(M0, mod1_wi, mod1_bi, xwA, BT, 300, 200);
    gemm_tn<float, bf16, true><<<g, 256, 0, stream>>>(M0, mod1_wi + 60000, mod1_bi + 300, xwB, BT, 300, 200);
  }
  gru_scan100_reg<<<dim3(B, 2), 320, 0, stream>>>(xwA, xwB, mod1_wh, mod1_bh, Mx, T);

  // ---- 7. encoder ----
  {
    dim3 g(BT / 64, (1200 + 63) / 64);
    gemm_tn<float, bf16, true><<<g, 256, 0, stream>>>(Mx, enc_wi, enc_bi, xwe, BT, 1200, 200);
  }
  gru_scan_enc_mw<<<dim3(B, 8), 320, 0, stream>>>(xwe, enc_wh, enc_bh, enc_out, h_all, flags, T);
  {
    dim3 g(BT / 64, (200 + 63) / 64);
    gemm_tn<float, float, false><<<g, 256, 0, stream>>>(enc_out, w1, nullptr, encw1, BT, 200, 400);
  }

  // ---- 8. pointer decoder ----
  decoder_small<<<1, 512, 0, stream>>>(dec_wh, dec_bi, dec_bh, w2, d2);
  logits_kernel<<<BT, 64, 0, stream>>>(encw1, d2, vt, out_f, T);
  log_softmax_T<<<B * 2, 256, 0, stream>>>(out_f, T);
}

// Round 4
// 4540.635 us; speedup vs baseline: 2.7157x; 1.4442x over previous
//
#include <hip/hip_runtime.h>
#include <hip/hip_bf16.h>

typedef __hip_bfloat16 bf16;
typedef unsigned long long u64;

#define DEV __device__ __forceinline__

DEV float to_f32(float x) { return x; }
DEV float to_f32(bf16 x) { return __bfloat162float(x); }
DEV void store_c(float* p, float v) { *p = v; }
DEV void store_c(bf16* p, float v) { *p = __float2bfloat16(v); }
DEV float sigmf(float x) { return 1.f / (1.f + __expf(-x)); }

// ---------------- embedding gather ----------------
__global__ void gather_embed(const int* __restrict__ idx, const float* __restrict__ embed,
                             float* __restrict__ out, int ntok) {
  int i = blockIdx.x * blockDim.x + threadIdx.x;
  if (i >= ntok * 100) return;
  int t = i / 100;
  int d = i - t * 100;
  out[i] = embed[(size_t)idx[t] * 100 + d];
}

// ---------------- generic tiled GEMM: C[M,N] = A[M,K] @ W[N,K]^T (+bias) ----------------
template <typename TA, typename TC, bool HAS_BIAS>
__global__ __launch_bounds__(256) void gemm_tn(
    const TA* __restrict__ A, const float* __restrict__ W,
    const float* __restrict__ bias, TC* __restrict__ C,
    int M, int N, int K) {
  __shared__ float As[16][64];
  __shared__ float Ws[16][64];
  const int m0 = blockIdx.x * 64;
  const int n0 = blockIdx.y * 64;
  const int tid = threadIdx.x;
  const int tx = tid & 15, ty = tid >> 4;
  const int r = tid & 63, cs = (tid >> 6) << 2;
  float acc[4][4] = {};
  for (int k0 = 0; k0 < K; k0 += 16) {
#pragma unroll
    for (int j = 0; j < 4; ++j) {
      int k = k0 + cs + j;
      As[cs + j][r] = (k < K) ? to_f32(A[(size_t)(m0 + r) * K + k]) : 0.f;
      int n = n0 + r;
      Ws[cs + j][r] = (k < K && n < N) ? W[(size_t)n * K + k] : 0.f;
    }
    __syncthreads();
#pragma unroll
    for (int kk = 0; kk < 16; ++kk) {
      float4 a4 = *(const float4*)(&As[kk][ty << 2]);
      float4 b4 = *(const float4*)(&Ws[kk][tx << 2]);
      float a[4] = {a4.x, a4.y, a4.z, a4.w};
      float b[4] = {b4.x, b4.y, b4.z, b4.w};
#pragma unroll
      for (int i = 0; i < 4; ++i)
#pragma unroll
        for (int j = 0; j < 4; ++j) acc[i][j] += a[i] * b[j];
    }
    __syncthreads();
  }
#pragma unroll
  for (int i = 0; i < 4; ++i) {
    int m = m0 + (ty << 2) + i;
#pragma unroll
    for (int j = 0; j < 4; ++j) {
      int n = n0 + (tx << 2) + j;
      if (n < N) {
        float v = acc[i][j];
        if (HAS_BIAS) v += bias[n];
        store_c(&C[(size_t)m * N + n], v);
      }
    }
  }
}

// ---------------- GRU scan H=100, register-resident weights, one WG per (batch,dir) ----------------
__global__ __launch_bounds__(320) void gru_scan100_reg(
    const bf16* __restrict__ xw_f, const bf16* __restrict__ xw_b,
    const float* __restrict__ wh,  // [2][300][100] (raw layout)
    const float* __restrict__ bh,  // [2][300]
    float* __restrict__ out,       // [B,T,200]
    int T) {
  const int b = blockIdx.x, dir = blockIdx.y;
  const bf16* xw = dir ? xw_b : xw_f;
  __shared__ float h_s[100];
  __shared__ float g_s[300];
  const int tid = threadIdx.x;
  float w[100];
  float bias = 0.f;
  if (tid < 300) {
    const float* wrow = wh + (size_t)dir * 30000 + (size_t)tid * 100;
#pragma unroll
    for (int c = 0; c < 25; ++c) {
      float4 v = *(const float4*)(wrow + 4 * c);
      w[4 * c] = v.x; w[4 * c + 1] = v.y; w[4 * c + 2] = v.z; w[4 * c + 3] = v.w;
    }
    bias = bh[dir * 300 + tid];
  }
  if (tid < 100) h_s[tid] = 0.f;
  __syncthreads();
  for (int step = 0; step < T; ++step) {
    int t = dir ? (T - 1 - step) : step;
    if (tid < 300) {
      float a0 = bias, a1 = 0.f, a2 = 0.f, a3 = 0.f;
#pragma unroll
      for (int c = 0; c < 25; ++c) {
        float4 h4 = *(const float4*)(&h_s[4 * c]);
        a0 += w[4 * c] * h4.x; a1 += w[4 * c + 1] * h4.y;
        a2 += w[4 * c + 2] * h4.z; a3 += w[4 * c + 3] * h4.w;
      }
      g_s[tid] = (a0 + a1) + (a2 + a3);
    }
    __syncthreads();
    if (tid < 100) {
      size_t base = ((size_t)b * T + t) * 300;
      float xr = to_f32(xw[base + tid]);
      float xz = to_f32(xw[base + 100 + tid]);
      float xn = to_f32(xw[base + 200 + tid]);
      float rr = sigmf(xr + g_s[tid]);
      float zz = sigmf(xz + g_s[100 + tid]);
      float nn = tanhf(xn + rr * g_s[200 + tid]);
      float hn = (1.f - zz) * nn + zz * h_s[tid];
      h_s[tid] = hn;
      out[((size_t)b * T + t) * 200 + dir * 100 + tid] = hn;
    }
    __syncthreads();
  }
}

// ---------------- encoder GRU scan H=400: 8 WGs/batch, tagged-value cross-WG exchange ------
// Each published h element is an 8B word {f32 value, u32 tag=step+1}, stored with a RELAXED
// agent-scope atomic (value+tag travel atomically together -> no ordering/flags needed).
// Readers poll their word until tag == t+1. Double-buffered by step parity: a producer
// cannot reach step t+3 before every WG consumed step t+1, so slot (t+1)&1 is never
// overwritten early. One MALL round-trip per step, no cache-maintenance instructions.
__global__ __launch_bounds__(640) void gru_scan_enc_tag(
    const bf16* __restrict__ xw,   // [B,T,1200]
    const float* __restrict__ wh,  // [1200,400] raw
    const float* __restrict__ bh,  // [1200]
    float* __restrict__ out,       // [B,T,400]
    u64* __restrict__ hx,          // [B,2,400] {value,tag} words (pre-zeroed EVERY call)
    int T) {
  const int b = blockIdx.x, s = blockIdx.y;
  __shared__ float h_s[400];
  __shared__ float g_s[150];
  const int tid = threadIdx.x;
  const int g = tid >> 2, p = tid & 3;  // gate g in [0,150), k-quarter p
  const bool active = (tid < 600);
  float w[100];
  float bias = 0.f;
  if (active) {
    int i = g % 50, grp = g / 50;  // grp: 0=r 1=z 2=n
    int gidx = grp * 400 + s * 50 + i;
    const float* wrow = wh + (size_t)gidx * 400 + p * 100;
#pragma unroll
    for (int c = 0; c < 25; ++c) {
      float4 v = *(const float4*)(wrow + 4 * c);
      w[4 * c] = v.x; w[4 * c + 1] = v.y; w[4 * c + 2] = v.z; w[4 * c + 3] = v.w;
    }
    if (p == 0) bias = bh[gidx];
  }
  for (int k = tid; k < 400; k += 640) h_s[k] = 0.f;
  __syncthreads();

  for (int t = 0; t < T; ++t) {
    // gate dot products: 150 gates x 4 k-quarters (reads full h_s)
    if (active) {
      float a0 = bias, a1 = 0.f, a2 = 0.f, a3 = 0.f;
      const int hb = p * 100;
#pragma unroll
      for (int c = 0; c < 25; ++c) {
        float4 h4 = *(const float4*)(&h_s[hb + 4 * c]);
        a0 += w[4 * c] * h4.x; a1 += w[4 * c + 1] * h4.y;
        a2 += w[4 * c + 2] * h4.z; a3 += w[4 * c + 3] * h4.w;
      }
      float acc = (a0 + a1) + (a2 + a3);
      acc += __shfl_xor(acc, 1);
      acc += __shfl_xor(acc, 2);
      if (p == 0) g_s[g] = acc;
    }
    __syncthreads();  // gates ready; everyone done READING h_s
    const int par = (t + 1) & 1;
    u64* hxp = hx + ((size_t)b * 2 + par) * 400;
    // slice-local h update (own 50 elements)
    if (tid < 50) {
      size_t base = ((size_t)b * T + t) * 1200;
      int i = s * 50 + tid;
      float xr = to_f32(xw[base + i]);
      float xz = to_f32(xw[base + 400 + i]);
      float xn = to_f32(xw[base + 800 + i]);
      float rr = sigmf(xr + g_s[tid]);
      float zz = sigmf(xz + g_s[50 + tid]);
      float nn = tanhf(xn + rr * g_s[100 + tid]);
      float hn = (1.f - zz) * nn + zz * h_s[i];
      out[((size_t)b * T + t) * 400 + i] = hn;
      h_s[i] = hn;  // local copy
      u64 pack = (u64)__float_as_uint(hn) | ((u64)(unsigned)(t + 1) << 32);
      __hip_atomic_store(&hxp[i], pack, __ATOMIC_RELAXED, __HIP_MEMORY_SCOPE_AGENT);
    }
    // pull the other 7 slices (each thread owns one h element; self-validating poll)
    if (tid < 400 && (tid / 50) != s) {
      const u64* src = &hxp[tid];
      u64 v;
      for (;;) {
        v = __hip_atomic_load(src, __ATOMIC_RELAXED, __HIP_MEMORY_SCOPE_AGENT);
        if ((unsigned)(v >> 32) == (unsigned)(t + 1)) break;
        __builtin_amdgcn_s_sleep(1);
      }
      h_s[tid] = __uint_as_float((unsigned)v);
    }
    __syncthreads();  // full h(t+1) assembled in h_s
  }
}

// ---------------- row · w (200-dim) -> scalar; one wave per row ----------------
__global__ __launch_bounds__(64) void rowdot200(const float* __restrict__ X, const float* __restrict__ w,
                                                float* __restrict__ out, int rows) {
  int r = blockIdx.x;
  int lane = threadIdx.x;
  const float* x = X + (size_t)r * 200;
  float s = x[lane] * w[lane] + x[lane + 64] * w[lane + 64] + x[lane + 128] * w[lane + 128];
  if (lane < 8) s += x[lane + 192] * w[lane + 192];
  for (int off = 32; off; off >>= 1) s += __shfl_down(s, off);
  if (lane == 0) out[r] = s;
}

// ---------------- attention: S row softmax -> c2q, row max -> smax ----------------
__global__ __launch_bounds__(256) void attn_main(
    const float* __restrict__ h,      // [B,T,200]
    const float* __restrict__ u,      // [B,64,200]
    const float* __restrict__ th,     // [B,T]
    const float* __restrict__ tu,     // [B,64]
    const float* __restrict__ w_sim,  // w3s at +400
    float* __restrict__ c2q,          // [B,T,200]
    float* __restrict__ smax,         // [B,T]
    int T) {
  const int b = blockIdx.x;
  const int t0 = blockIdx.y * 32;
  __shared__ float u_s[64 * 201];
  __shared__ float tu_s[64];
  __shared__ float w3_s[200];
  __shared__ float hw3_s[200];
  __shared__ float Sp[4][64];
  __shared__ float A_s[64];
  const int tid = threadIdx.x;
  for (int i = tid; i < 64 * 200; i += 256) {
    int l = i / 200, d = i - l * 200;
    u_s[l * 201 + d] = u[((size_t)b * 64 + l) * 200 + d];
  }
  if (tid < 64) tu_s[tid] = tu[b * 64 + tid];
  if (tid < 200) w3_s[tid] = w_sim[400 + tid];
  __syncthreads();
  for (int tt = 0; tt < 32; ++tt) {
    int t = t0 + tt;
    if (tid < 200) hw3_s[tid] = h[((size_t)b * T + t) * 200 + tid] * w3_s[tid];
    __syncthreads();
    int l = tid & 63, q = tid >> 6;
    float p = 0.f;
    for (int d = q * 50; d < q * 50 + 50; ++d) p += hw3_s[d] * u_s[l * 201 + d];
    Sp[q][l] = p;
    __syncthreads();
    if (tid < 64) {
      float s = th[b * T + t] + tu_s[l] + Sp[0][l] + Sp[1][l] + Sp[2][l] + Sp[3][l];
      float m = s;
      for (int off = 32; off; off >>= 1) m = fmaxf(m, __shfl_xor(m, off));
      float e = __expf(s - m);
      float ssum = e;
      for (int off = 32; off; off >>= 1) ssum += __shfl_xor(ssum, off);
      A_s[l] = e / ssum;
      if (l == 0) smax[b * T + t] = m;
    }
    __syncthreads();
    if (tid < 200) {
      float acc = 0.f;
      for (int l2 = 0; l2 < 64; ++l2) acc += A_s[l2] * u_s[l2 * 201 + tid];
      c2q[((size_t)b * T + t) * 200 + tid] = acc;
    }
    __syncthreads();
  }
}

// ---------------- softmax over T (per batch row) ----------------
__global__ __launch_bounds__(256) void softmax_T(const float* __restrict__ in, float* __restrict__ outv, int T) {
  int b = blockIdx.x;
  int tid = threadIdx.x;
  __shared__ float red[256];
  float m = -1e30f;
  for (int t = tid; t < T; t += 256) m = fmaxf(m, in[b * T + t]);
  red[tid] = m;
  __syncthreads();
  for (int s = 128; s; s >>= 1) {
    if (tid < s) red[tid] = fmaxf(red[tid], red[tid + s]);
    __syncthreads();
  }
  m = red[0];
  __syncthreads();
  float sum = 0.f;
  for (int t = tid; t < T; t += 256) sum += __expf(in[b * T + t] - m);
  red[tid] = sum;
  __syncthreads();
  for (int s = 128; s; s >>= 1) {
    if (tid < s) red[tid] += red[tid + s];
    __syncthreads();
  }
  float inv = 1.f / red[0];
  for (int t = tid; t < T; t += 256) outv[b * T + t] = __expf(in[b * T + t] - m) * inv;
}

// ---------------- q2c[b,d] = sum_t batt[b,t] * h[b,t,d] ----------------
__global__ __launch_bounds__(256) void q2c_kernel(const float* __restrict__ batt, const float* __restrict__ h,
                                                  float* __restrict__ q2c, int T) {
  int b = blockIdx.x;
  int tid = threadIdx.x;
  if (tid < 200) {
    float acc = 0.f;
    for (int t = 0; t < T; ++t) acc += batt[b * T + t] * h[((size_t)b * T + t) * 200 + tid];
    q2c[b * 200 + tid] = acc;
  }
}

// ---------------- G = [h, c2q, h*c2q, h*q2c] (bf16) ----------------
__global__ void build_G(const float* __restrict__ h, const float* __restrict__ c2q,
                        const float* __restrict__ q2c, bf16* __restrict__ G, int T) {
  size_t i = (size_t)blockIdx.x * blockDim.x + threadIdx.x;
  if (i >= (size_t)32 * T * 200) return;
  size_t row = i / 200;
  int d = (int)(i - row * 200);
  int b = (int)(row / T);
  float hv = h[i];
  float cv = c2q[i];
  float qv = q2c[b * 200 + d];
  bf16* g = G + row * 800;
  g[d] = __float2bfloat16(hv);
  g[200 + d] = __float2bfloat16(cv);
  g[400 + d] = __float2bfloat16(hv * cv);
  g[600 + d] = __float2bfloat16(hv * qv);
}

// ---------------- decoder (batch-uniform since dec_in == 0): d2[2][200] ----------------
__global__ __launch_bounds__(512) void decoder_small(
    const float* __restrict__ dwh,  // [1200,400]
    const float* __restrict__ dbi, const float* __restrict__ dbh,
    const float* __restrict__ w2,  // [200,400]
    float* __restrict__ d2out) {   // [2][200]
  __shared__ float hid[400];
  __shared__ float hid2[400];
  __shared__ float gh[1200];
  const int tid = threadIdx.x;
  if (tid < 400) {
    float r = sigmf(dbi[tid] + dbh[tid]);
    float z = sigmf(dbi[400 + tid] + dbh[400 + tid]);
    float n = tanhf(dbi[800 + tid] + r * dbh[800 + tid]);
    hid[tid] = (1.f - z) * n;
  }
  __syncthreads();
  if (tid < 200) {
    float a = 0.f;
    for (int k = 0; k < 400; ++k) a += w2[(size_t)tid * 400 + k] * hid[k];
    d2out[tid] = a;
  }
  for (int j = tid; j < 1200; j += 512) {
    float a = dbh[j];
    for (int k = 0; k < 400; ++k) a += dwh[(size_t)j * 400 + k] * hid[k];
    gh[j] = a;
  }
  __syncthreads();
  if (tid < 400) {
    float r = sigmf(dbi[tid] + gh[tid]);
    float z = sigmf(dbi[400 + tid] + gh[400 + tid]);
    float n = tanhf(dbi[800 + tid] + r * gh[800 + tid]);
    hid2[tid] = (1.f - z) * n + z * hid[tid];
  }
  __syncthreads();
  if (tid < 200) {
    float a = 0.f;
    for (int k = 0; k < 400; ++k) a += w2[(size_t)tid * 400 + k] * hid2[k];
    d2out[200 + tid] = a;
  }
}

// ---------------- logits: out[b,it,t] = sum_p tanh(encw1[b,t,p]+d2[it][p])*vt[p] ----------------
__global__ __launch_bounds__(64) void logits_kernel(
    const float* __restrict__ encw1,  // [B,T,200]
    const float* __restrict__ d2,     // [2][200]
    const float* __restrict__ vt,     // [200]
    float* __restrict__ outp,         // [B,2,T]
    int T) {
  int row = blockIdx.x;  // b*T + t
  int b = row / T, t = row - b * T;
  int lane = threadIdx.x;
  const float* e = encw1 + (size_t)row * 200;
  float s0 = 0.f, s1 = 0.f;
  for (int p = lane; p < 200; p += 64) {
    float ev = e[p], v = vt[p];
    s0 += tanhf(ev + d2[p]) * v;
    s1 += tanhf(ev + d2[200 + p]) * v;
  }
  for (int off = 32; off; off >>= 1) {
    s0 += __shfl_down(s0, off);
    s1 += __shfl_down(s1, off);
  }
  if (lane == 0) {
    outp[((size_t)b * 2 + 0) * T + t] = s0;
    outp[((size_t)b * 2 + 1) * T + t] = s1;
  }
}

// ---------------- log_softmax over T, in-place ----------------
__global__ __launch_bounds__(256) void log_softmax_T(float* __restrict__ x, int T) {
  int row = blockIdx.x;
  float* p = x + (size_t)row * T;
  __shared__ float red[256];
  int tid = threadIdx.x;
  float m = -1e30f;
  for (int t = tid; t < T; t += 256) m = fmaxf(m, p[t]);
  red[tid] = m;
  __syncthreads();
  for (int s = 128; s; s >>= 1) {
    if (tid < s) red[tid] = fmaxf(red[tid], red[tid + s]);
    __syncthreads();
  }
  m = red[0];
  __syncthreads();
  float sum = 0.f;
  for (int t = tid; t < T; t += 256) sum += __expf(p[t] - m);
  red[tid] = sum;
  __syncthreads();
  for (int s = 128; s; s >>= 1) {
    if (tid < s) red[tid] += red[tid + s];
    __syncthreads();
  }
  float lse = m + __logf(red[0]);
  __syncthreads();
  for (int t = tid; t < T; t += 256) p[t] = p[t] - lse;
}

extern "C" void kernel_launch(void* const* d_in, const int* in_sizes, int n_in,
                              void* d_out, int out_size, void* d_ws, size_t ws_size,
                              hipStream_t stream) {
  (void)in_sizes; (void)n_in; (void)out_size; (void)ws_size;
  const int B = 32, T = 512, L = 64;
  const int BT = B * T;    // 16384
  const int BL = B * L;    // 2048

  const int* x_word = (const int*)d_in[0];
  const int* x_query = (const int*)d_in[1];
  const float* embed = (const float*)d_in[2];
  const float* ctx_wi = (const float*)d_in[3];
  const float* ctx_wh = (const float*)d_in[4];
  const float* ctx_bi = (const float*)d_in[5];
  const float* ctx_bh = (const float*)d_in[6];
  const float* mod0_wi = (const float*)d_in[7];
  const float* mod0_wh = (const float*)d_in[8];
  const float* mod0_bi = (const float*)d_in[9];
  const float* mod0_bh = (const float*)d_in[10];
  const float* mod1_wi = (const float*)d_in[11];
  const float* mod1_wh = (const float*)d_in[12];
  const float* mod1_bi = (const float*)d_in[13];
  const float* mod1_bh = (const float*)d_in[14];
  const float* w_sim = (const float*)d_in[15];
  const float* enc_wi = (const float*)d_in[16];
  const float* enc_wh = (const float*)d_in[17];
  const float* enc_bi = (const float*)d_in[18];
  const float* enc_bh = (const float*)d_in[19];
  const float* dec_wh = (const float*)d_in[21];
  const float* dec_bi = (const float*)d_in[22];
  const float* dec_bh = (const float*)d_in[23];
  const float* w1 = (const float*)d_in[24];
  const float* w2 = (const float*)d_in[25];
  const float* vt = (const float*)d_in[26];
  float* out_f = (float*)d_out;

  // ---- workspace layout (region reuse) ----
  char* ws = (char*)d_ws;
  size_t off = 0;
  auto alloc = [&](size_t bytes) -> void* {
    void* p = ws + off;
    off += (bytes + 255) & ~(size_t)255;
    return p;
  };
  u64* hx = (u64*)alloc((size_t)B * 2 * 400 * 8);  // tagged h-exchange words
  float* ew = (float*)alloc((size_t)BT * 100 * 4);
  float* eq = (float*)alloc((size_t)BL * 100 * 4);
  char* RA = (char*)alloc((size_t)BT * 1200 * 2);  // 39.3 MB
  bf16* xwA = (bf16*)RA;                            // [BT,300] bf16
  bf16* xwB = (bf16*)(RA + (size_t)BT * 300 * 2);
  bf16* xwe = (bf16*)RA;                            // [BT,1200] bf16 (later)
  bf16* xwqF = (bf16*)alloc((size_t)BL * 300 * 2);
  bf16* xwqB = (bf16*)alloc((size_t)BL * 300 * 2);
  char* RB = (char*)alloc((size_t)BT * 800 * 2);   // 26.2 MB
  bf16* G = (bf16*)RB;
  float* enc_out = (float*)RB;                      // [BT,400] f32 (later, same size)
  char* RC = (char*)alloc((size_t)2 * BT * 200 * 4);  // 26.2 MB
  float* h_cat = (float*)RC;                        // [BT,200]
  float* c2q = (float*)(RC + (size_t)BT * 200 * 4);
  float* M0 = c2q;                                  // reuse (c2q dead after G)
  float* Mx = h_cat;                                // reuse (h dead after G)
  float* encw1 = c2q;                               // reuse (M0 dead after xw1)
  float* u_cat = (float*)alloc((size_t)BL * 200 * 4);
  float* th = (float*)alloc((size_t)BT * 4);
  float* tu = (float*)alloc((size_t)BL * 4);
  float* smaxb = (float*)alloc((size_t)BT * 4);
  float* batt = (float*)alloc((size_t)BT * 4);
  float* q2cb = (float*)alloc((size_t)B * 200 * 4);
  float* d2 = (float*)alloc((size_t)400 * 4);

  // ---- 0. zero hx EVERY call: stale tags from a previous replay could otherwise
  //         satisfy a poll with old data (harness does not re-poison between replays).
  hipMemsetAsync(hx, 0, (size_t)B * 2 * 400 * 8, stream);

  // ---- 1. embedding gathers ----
  gather_embed<<<(BT * 100 + 255) / 256, 256, 0, stream>>>(x_word, embed, ew, BT);
  gather_embed<<<(BL * 100 + 255) / 256, 256, 0, stream>>>(x_query, embed, eq, BL);

  // ---- 2. ctx input projections ----
  {
    dim3 g(BT / 64, (300 + 63) / 64);
    gemm_tn<float, bf16, true><<<g, 256, 0, stream>>>(ew, ctx_wi, ctx_bi, xwA, BT, 300, 100);
    gemm_tn<float, bf16, true><<<g, 256, 0, stream>>>(ew, ctx_wi + 30000, ctx_bi + 300, xwB, BT, 300, 100);
    dim3 gq(BL / 64, (300 + 63) / 64);
    gemm_tn<float, bf16, true><<<gq, 256, 0, stream>>>(eq, ctx_wi, ctx_bi, xwqF, BL, 300, 100);
    gemm_tn<float, bf16, true><<<gq, 256, 0, stream>>>(eq, ctx_wi + 30000, ctx_bi + 300, xwqB, BL, 300, 100);
  }

  // ---- 3. ctx scans (register-resident weights) ----
  gru_scan100_reg<<<dim3(B, 2), 320, 0, stream>>>(xwA, xwB, ctx_wh, ctx_bh, h_cat, T);
  gru_scan100_reg<<<dim3(B, 2), 320, 0, stream>>>(xwqF, xwqB, ctx_wh, ctx_bh, u_cat, L);

  // ---- 4. attention ----
  rowdot200<<<BT, 64, 0, stream>>>(h_cat, w_sim, th, BT);
  rowdot200<<<BL, 64, 0, stream>>>(u_cat, w_sim + 200, tu, BL);
  attn_main<<<dim3(B, T / 32), 256, 0, stream>>>(h_cat, u_cat, th, tu, w_sim, c2q, smaxb, T);
  softmax_T<<<B, 256, 0, stream>>>(smaxb, batt, T);
  q2c_kernel<<<B, 256, 0, stream>>>(batt, h_cat, q2cb, T);
  build_G<<<(BT * 200 + 255) / 256, 256, 0, stream>>>(h_cat, c2q, q2cb, G, T);

  // ---- 5. mod0 ----
  {
    dim3 g(BT / 64, (300 + 63) / 64);
    gemm_tn<bf16, bf16, true><<<g, 256, 0, stream>>>(G, mod0_wi, mod0_bi, xwA, BT, 300, 800);
    gemm_tn<bf16, bf16, true><<<g, 256, 0, stream>>>(G, mod0_wi + 240000, mod0_bi + 300, xwB, BT, 300, 800);
  }
  gru_scan100_reg<<<dim3(B, 2), 320, 0, stream>>>(xwA, xwB, mod0_wh, mod0_bh, M0, T);

  // ---- 6. mod1 ----
  {
    dim3 g(BT / 64, (300 + 63) / 64);
    gemm_tn<float, bf16, true><<<g, 256, 0, stream>>>(M0, mod1_wi, mod1_bi, xwA, BT, 300, 200);
    gemm_tn<float, bf16, true><<<g, 256, 0, stream>>>(M0, mod1_wi + 60000, mod1_bi + 300, xwB, BT, 300, 200);
  }
  gru_scan100_reg<<<dim3(B, 2), 320, 0, stream>>>(xwA, xwB, mod1_wh, mod1_bh, Mx, T);

  // ---- 7. encoder ----
  {
    dim3 g(BT / 64, (1200 + 63) / 64);
    gemm_tn<float, bf16, true><<<g, 256, 0, stream>>>(Mx, enc_wi, enc_bi, xwe, BT, 1200, 200);
  }
  gru_scan_enc_tag<<<dim3(B, 8), 640, 0, stream>>>(xwe, enc_wh, enc_bh, enc_out, hx, T);
  {
    dim3 g(BT / 64, (200 + 63) / 64);
    gemm_tn<float, float, false><<<g, 256, 0, stream>>>(enc_out, w1, nullptr, encw1, BT, 200, 400);
  }

  // ---- 8. pointer decoder ----
  decoder_small<<<1, 512, 0, stream>>>(dec_wh, dec_bi, dec_bh, w2, d2);
  logits_kernel<<<BT, 64, 0, stream>>>(encw1, d2, vt, out_f, T);
  log_softmax_T<<<B * 2, 256, 0, stream>>>(out_f, T);
}

// Round 5
// 4047.630 us; speedup vs baseline: 3.0465x; 1.1218x over previous
//
#include <hip/hip_runtime.h>
#include <hip/hip_bf16.h>

typedef __hip_bfloat16 bf16;
typedef unsigned long long u64;

#define DEV __device__ __forceinline__

DEV float to_f32(float x) { return x; }
DEV float to_f32(bf16 x) { return __bfloat162float(x); }
DEV void store_c(float* p, float v) { *p = v; }
DEV void store_c(bf16* p, float v) { *p = __float2bfloat16(v); }
DEV float sigmf(float x) { return 1.f / (1.f + __expf(-x)); }

DEV float bfbits(unsigned short u) { return __uint_as_float((unsigned)u << 16); }
DEV float4 load4w(const float* p) { return *(const float4*)p; }
DEV float4 load4w(const bf16* p) {
  ushort4 u = *(const ushort4*)p;
  float4 r;
  r.x = bfbits(u.x); r.y = bfbits(u.y); r.z = bfbits(u.z); r.w = bfbits(u.w);
  return r;
}

// ---------------- embedding gather ----------------
__global__ void gather_embed(const int* __restrict__ idx, const float* __restrict__ embed,
                             float* __restrict__ out, int ntok) {
  int i = blockIdx.x * blockDim.x + threadIdx.x;
  if (i >= ntok * 100) return;
  int t = i / 100;
  int d = i - t * 100;
  out[i] = embed[(size_t)idx[t] * 100 + d];
}

// ---------------- tiled GEMM: C[M,N] = A[M,K] @ W[N,K]^T (+bias), coalesced staging -------
// Staging: thread (r2=tid>>2, c4=(tid&3)*4) loads a contiguous 4-vector of row r2 and
// writes transposed As[k][r2] (stride 68: 16B-aligned reads, <=2-way write conflicts).
template <typename TA, typename TC, bool HAS_BIAS>
__global__ __launch_bounds__(256) void gemm_tn(
    const TA* __restrict__ A, const float* __restrict__ W,
    const float* __restrict__ bias, TC* __restrict__ C,
    int M, int N, int K) {
  __shared__ float As[16][68];
  __shared__ float Ws[16][68];
  const int m0 = blockIdx.x * 64;
  const int n0 = blockIdx.y * 64;
  const int tid = threadIdx.x;
  const int tx = tid & 15, ty = tid >> 4;      // compute mapping: 16x16 threads, 4x4 each
  const int r2 = tid >> 2, c4 = (tid & 3) * 4; // staging mapping
  const int nW = n0 + r2;
  float acc[4][4] = {};
  for (int k0 = 0; k0 < K; k0 += 16) {
    if (k0 + 16 <= K) {
      float4 av = load4w(&A[(size_t)(m0 + r2) * K + k0 + c4]);
      As[c4 + 0][r2] = av.x; As[c4 + 1][r2] = av.y;
      As[c4 + 2][r2] = av.z; As[c4 + 3][r2] = av.w;
      if (nW < N) {
        float4 wv = load4w(&W[(size_t)nW * K + k0 + c4]);
        Ws[c4 + 0][r2] = wv.x; Ws[c4 + 1][r2] = wv.y;
        Ws[c4 + 2][r2] = wv.z; Ws[c4 + 3][r2] = wv.w;
      } else {
        Ws[c4 + 0][r2] = 0.f; Ws[c4 + 1][r2] = 0.f;
        Ws[c4 + 2][r2] = 0.f; Ws[c4 + 3][r2] = 0.f;
      }
    } else {
#pragma unroll
      for (int j = 0; j < 4; ++j) {
        int k = k0 + c4 + j;
        As[c4 + j][r2] = (k < K) ? to_f32(A[(size_t)(m0 + r2) * K + k]) : 0.f;
        Ws[c4 + j][r2] = (k < K && nW < N) ? W[(size_t)nW * K + k] : 0.f;
      }
    }
    __syncthreads();
#pragma unroll
    for (int kk = 0; kk < 16; ++kk) {
      float4 a4 = *(const float4*)(&As[kk][ty << 2]);
      float4 b4 = *(const float4*)(&Ws[kk][tx << 2]);
      float a[4] = {a4.x, a4.y, a4.z, a4.w};
      float b[4] = {b4.x, b4.y, b4.z, b4.w};
#pragma unroll
      for (int i = 0; i < 4; ++i)
#pragma unroll
        for (int j = 0; j < 4; ++j) acc[i][j] += a[i] * b[j];
    }
    __syncthreads();
  }
#pragma unroll
  for (int i = 0; i < 4; ++i) {
    int m = m0 + (ty << 2) + i;
#pragma unroll
    for (int j = 0; j < 4; ++j) {
      int n = n0 + (tx << 2) + j;
      if (n < N) {
        float v = acc[i][j];
        if (HAS_BIAS) v += bias[n];
        store_c(&C[(size_t)m * N + n], v);
      }
    }
  }
}

// ---------------- GRU scan H=100, register-resident weights, one WG per (batch,dir) ----------------
__global__ __launch_bounds__(320) void gru_scan100_reg(
    const bf16* __restrict__ xw_f, const bf16* __restrict__ xw_b,
    const float* __restrict__ wh,  // [2][300][100] (raw layout)
    const float* __restrict__ bh,  // [2][300]
    float* __restrict__ out,       // [B,T,200]
    int T) {
  const int b = blockIdx.x, dir = blockIdx.y;
  const bf16* xw = dir ? xw_b : xw_f;
  __shared__ float h_s[100];
  __shared__ float g_s[300];
  const int tid = threadIdx.x;
  float w[100];
  float bias = 0.f;
  if (tid < 300) {
    const float* wrow = wh + (size_t)dir * 30000 + (size_t)tid * 100;
#pragma unroll
    for (int c = 0; c < 25; ++c) {
      float4 v = *(const float4*)(wrow + 4 * c);
      w[4 * c] = v.x; w[4 * c + 1] = v.y; w[4 * c + 2] = v.z; w[4 * c + 3] = v.w;
    }
    bias = bh[dir * 300 + tid];
  }
  if (tid < 100) h_s[tid] = 0.f;
  __syncthreads();
  for (int step = 0; step < T; ++step) {
    int t = dir ? (T - 1 - step) : step;
    if (tid < 300) {
      float a0 = bias, a1 = 0.f, a2 = 0.f, a3 = 0.f;
#pragma unroll
      for (int c = 0; c < 25; ++c) {
        float4 h4 = *(const float4*)(&h_s[4 * c]);
        a0 += w[4 * c] * h4.x; a1 += w[4 * c + 1] * h4.y;
        a2 += w[4 * c + 2] * h4.z; a3 += w[4 * c + 3] * h4.w;
      }
      g_s[tid] = (a0 + a1) + (a2 + a3);
    }
    __syncthreads();
    if (tid < 100) {
      size_t base = ((size_t)b * T + t) * 300;
      float xr = to_f32(xw[base + tid]);
      float xz = to_f32(xw[base + 100 + tid]);
      float xn = to_f32(xw[base + 200 + tid]);
      float rr = sigmf(xr + g_s[tid]);
      float zz = sigmf(xz + g_s[100 + tid]);
      float nn = tanhf(xn + rr * g_s[200 + tid]);
      float hn = (1.f - zz) * nn + zz * h_s[tid];
      h_s[tid] = hn;
      out[((size_t)b * T + t) * 200 + dir * 100 + tid] = hn;
    }
    __syncthreads();
  }
}

// ---------------- encoder GRU scan H=400: 8 WGs/batch, tagged-value cross-WG exchange ------
__global__ __launch_bounds__(640) void gru_scan_enc_tag(
    const bf16* __restrict__ xw,   // [B,T,1200]
    const float* __restrict__ wh,  // [1200,400] raw
    const float* __restrict__ bh,  // [1200]
    float* __restrict__ out,       // [B,T,400]
    u64* __restrict__ hx,          // [B,2,400] {value,tag} words (pre-zeroed EVERY call)
    int T) {
  const int b = blockIdx.x, s = blockIdx.y;
  __shared__ float h_s[400];
  __shared__ float g_s[150];
  const int tid = threadIdx.x;
  const int g = tid >> 2, p = tid & 3;  // gate g in [0,150), k-quarter p
  const bool active = (tid < 600);
  float w[100];
  float bias = 0.f;
  if (active) {
    int i = g % 50, grp = g / 50;  // grp: 0=r 1=z 2=n
    int gidx = grp * 400 + s * 50 + i;
    const float* wrow = wh + (size_t)gidx * 400 + p * 100;
#pragma unroll
    for (int c = 0; c < 25; ++c) {
      float4 v = *(const float4*)(wrow + 4 * c);
      w[4 * c] = v.x; w[4 * c + 1] = v.y; w[4 * c + 2] = v.z; w[4 * c + 3] = v.w;
    }
    if (p == 0) bias = bh[gidx];
  }
  for (int k = tid; k < 400; k += 640) h_s[k] = 0.f;
  __syncthreads();

  for (int t = 0; t < T; ++t) {
    if (active) {
      float a0 = bias, a1 = 0.f, a2 = 0.f, a3 = 0.f;
      const int hb = p * 100;
#pragma unroll
      for (int c = 0; c < 25; ++c) {
        float4 h4 = *(const float4*)(&h_s[hb + 4 * c]);
        a0 += w[4 * c] * h4.x; a1 += w[4 * c + 1] * h4.y;
        a2 += w[4 * c + 2] * h4.z; a3 += w[4 * c + 3] * h4.w;
      }
      float acc = (a0 + a1) + (a2 + a3);
      acc += __shfl_xor(acc, 1);
      acc += __shfl_xor(acc, 2);
      if (p == 0) g_s[g] = acc;
    }
    __syncthreads();  // gates ready; everyone done READING h_s
    const int par = (t + 1) & 1;
    u64* hxp = hx + ((size_t)b * 2 + par) * 400;
    if (tid < 50) {
      size_t base = ((size_t)b * T + t) * 1200;
      int i = s * 50 + tid;
      float xr = to_f32(xw[base + i]);
      float xz = to_f32(xw[base + 400 + i]);
      float xn = to_f32(xw[base + 800 + i]);
      float rr = sigmf(xr + g_s[tid]);
      float zz = sigmf(xz + g_s[50 + tid]);
      float nn = tanhf(xn + rr * g_s[100 + tid]);
      float hn = (1.f - zz) * nn + zz * h_s[i];
      out[((size_t)b * T + t) * 400 + i] = hn;
      h_s[i] = hn;  // local copy
      u64 pack = (u64)__float_as_uint(hn) | ((u64)(unsigned)(t + 1) << 32);
      __hip_atomic_store(&hxp[i], pack, __ATOMIC_RELAXED, __HIP_MEMORY_SCOPE_AGENT);
    }
    if (tid < 400 && (tid / 50) != s) {
      const u64* src = &hxp[tid];
      u64 v;
      for (;;) {
        v = __hip_atomic_load(src, __ATOMIC_RELAXED, __HIP_MEMORY_SCOPE_AGENT);
        if ((unsigned)(v >> 32) == (unsigned)(t + 1)) break;
        __builtin_amdgcn_s_sleep(1);
      }
      h_s[tid] = __uint_as_float((unsigned)v);
    }
    __syncthreads();  // full h(t+1) assembled in h_s
  }
}

// ---------------- row · w (200-dim) -> scalar; one wave per row ----------------
__global__ __launch_bounds__(64) void rowdot200(const float* __restrict__ X, const float* __restrict__ w,
                                                float* __restrict__ out, int rows) {
  int r = blockIdx.x;
  int lane = threadIdx.x;
  const float* x = X + (size_t)r * 200;
  float s = x[lane] * w[lane] + x[lane + 64] * w[lane + 64] + x[lane + 128] * w[lane + 128];
  if (lane < 8) s += x[lane + 192] * w[lane + 192];
  for (int off = 32; off; off >>= 1) s += __shfl_down(s, off);
  if (lane == 0) out[r] = s;
}

// ---------------- attention: S row softmax -> c2q, row max -> smax ----------------
__global__ __launch_bounds__(256) void attn_main(
    const float* __restrict__ h,      // [B,T,200]
    const float* __restrict__ u,      // [B,64,200]
    const float* __restrict__ th,     // [B,T]
    const float* __restrict__ tu,     // [B,64]
    const float* __restrict__ w_sim,  // w3s at +400
    float* __restrict__ c2q,          // [B,T,200]
    float* __restrict__ smax,         // [B,T]
    int T) {
  const int b = blockIdx.x;
  const int t0 = blockIdx.y * 32;
  __shared__ float u_s[64 * 201];
  __shared__ float tu_s[64];
  __shared__ float w3_s[200];
  __shared__ float hw3_s[200];
  __shared__ float Sp[4][64];
  __shared__ float A_s[64];
  const int tid = threadIdx.x;
  for (int i = tid; i < 64 * 200; i += 256) {
    int l = i / 200, d = i - l * 200;
    u_s[l * 201 + d] = u[((size_t)b * 64 + l) * 200 + d];
  }
  if (tid < 64) tu_s[tid] = tu[b * 64 + tid];
  if (tid < 200) w3_s[tid] = w_sim[400 + tid];
  __syncthreads();
  for (int tt = 0; tt < 32; ++tt) {
    int t = t0 + tt;
    if (tid < 200) hw3_s[tid] = h[((size_t)b * T + t) * 200 + tid] * w3_s[tid];
    __syncthreads();
    int l = tid & 63, q = tid >> 6;
    float p = 0.f;
    for (int d = q * 50; d < q * 50 + 50; ++d) p += hw3_s[d] * u_s[l * 201 + d];
    Sp[q][l] = p;
    __syncthreads();
    if (tid < 64) {
      float s = th[b * T + t] + tu_s[l] + Sp[0][l] + Sp[1][l] + Sp[2][l] + Sp[3][l];
      float m = s;
      for (int off = 32; off; off >>= 1) m = fmaxf(m, __shfl_xor(m, off));
      float e = __expf(s - m);
      float ssum = e;
      for (int off = 32; off; off >>= 1) ssum += __shfl_xor(ssum, off);
      A_s[l] = e / ssum;
      if (l == 0) smax[b * T + t] = m;
    }
    __syncthreads();
    if (tid < 200) {
      float acc = 0.f;
      for (int l2 = 0; l2 < 64; ++l2) acc += A_s[l2] * u_s[l2 * 201 + tid];
      c2q[((size_t)b * T + t) * 200 + tid] = acc;
    }
    __syncthreads();
  }
}

// ---------------- softmax over T (per batch row) ----------------
__global__ __launch_bounds__(256) void softmax_T(const float* __restrict__ in, float* __restrict__ outv, int T) {
  int b = blockIdx.x;
  int tid = threadIdx.x;
  __shared__ float red[256];
  float m = -1e30f;
  for (int t = tid; t < T; t += 256) m = fmaxf(m, in[b * T + t]);
  red[tid] = m;
  __syncthreads();
  for (int s = 128; s; s >>= 1) {
    if (tid < s) red[tid] = fmaxf(red[tid], red[tid + s]);
    __syncthreads();
  }
  m = red[0];
  __syncthreads();
  float sum = 0.f;
  for (int t = tid; t < T; t += 256) sum += __expf(in[b * T + t] - m);
  red[tid] = sum;
  __syncthreads();
  for (int s = 128; s; s >>= 1) {
    if (tid < s) red[tid] += red[tid + s];
    __syncthreads();
  }
  float inv = 1.f / red[0];
  for (int t = tid; t < T; t += 256) outv[b * T + t] = __expf(in[b * T + t] - m) * inv;
}

// ---------------- q2c[b,d] = sum_t batt[b,t] * h[b,t,d] ----------------
__global__ __launch_bounds__(256) void q2c_kernel(const float* __restrict__ batt, const float* __restrict__ h,
                                                  float* __restrict__ q2c, int T) {
  int b = blockIdx.x;
  int tid = threadIdx.x;
  if (tid < 200) {
    float acc = 0.f;
    for (int t = 0; t < T; ++t) acc += batt[b * T + t] * h[((size_t)b * T + t) * 200 + tid];
    q2c[b * 200 + tid] = acc;
  }
}

// ---------------- G = [h, c2q, h*c2q, h*q2c] (bf16) ----------------
__global__ void build_G(const float* __restrict__ h, const float* __restrict__ c2q,
                        const float* __restrict__ q2c, bf16* __restrict__ G, int T) {
  size_t i = (size_t)blockIdx.x * blockDim.x + threadIdx.x;
  if (i >= (size_t)32 * T * 200) return;
  size_t row = i / 200;
  int d = (int)(i - row * 200);
  int b = (int)(row / T);
  float hv = h[i];
  float cv = c2q[i];
  float qv = q2c[b * 200 + d];
  bf16* g = G + row * 800;
  g[d] = __float2bfloat16(hv);
  g[200 + d] = __float2bfloat16(cv);
  g[400 + d] = __float2bfloat16(hv * cv);
  g[600 + d] = __float2bfloat16(hv * qv);
}

// ---------------- decoder (batch-uniform since dec_in == 0): d2[2][200] ----------------
__global__ __launch_bounds__(512) void decoder_small(
    const float* __restrict__ dwh,  // [1200,400]
    const float* __restrict__ dbi, const float* __restrict__ dbh,
    const float* __restrict__ w2,  // [200,400]
    float* __restrict__ d2out) {   // [2][200]
  __shared__ float hid[400];
  __shared__ float hid2[400];
  __shared__ float gh[1200];
  const int tid = threadIdx.x;
  if (tid < 400) {
    float r = sigmf(dbi[tid] + dbh[tid]);
    float z = sigmf(dbi[400 + tid] + dbh[400 + tid]);
    float n = tanhf(dbi[800 + tid] + r * dbh[800 + tid]);
    hid[tid] = (1.f - z) * n;
  }
  __syncthreads();
  if (tid < 200) {
    float a = 0.f;
    for (int k = 0; k < 400; ++k) a += w2[(size_t)tid * 400 + k] * hid[k];
    d2out[tid] = a;
  }
  for (int j = tid; j < 1200; j += 512) {
    float a = dbh[j];
    for (int k = 0; k < 400; ++k) a += dwh[(size_t)j * 400 + k] * hid[k];
    gh[j] = a;
  }
  __syncthreads();
  if (tid < 400) {
    float r = sigmf(dbi[tid] + gh[tid]);
    float z = sigmf(dbi[400 + tid] + gh[400 + tid]);
    float n = tanhf(dbi[800 + tid] + r * gh[800 + tid]);
    hid2[tid] = (1.f - z) * n + z * hid[tid];
  }
  __syncthreads();
  if (tid < 200) {
    float a = 0.f;
    for (int k = 0; k < 400; ++k) a += w2[(size_t)tid * 400 + k] * hid2[k];
    d2out[200 + tid] = a;
  }
}

// ---------------- logits: out[b,it,t] = sum_p tanh(encw1[b,t,p]+d2[it][p])*vt[p] ----------------
__global__ __launch_bounds__(64) void logits_kernel(
    const float* __restrict__ encw1,  // [B,T,200]
    const float* __restrict__ d2,     // [2][200]
    const float* __restrict__ vt,     // [200]
    float* __restrict__ outp,         // [B,2,T]
    int T) {
  int row = blockIdx.x;  // b*T + t
  int b = row / T, t = row - b * T;
  int lane = threadIdx.x;
  const float* e = encw1 + (size_t)row * 200;
  float s0 = 0.f, s1 = 0.f;
  for (int p = lane; p < 200; p += 64) {
    float ev = e[p], v = vt[p];
    s0 += tanhf(ev + d2[p]) * v;
    s1 += tanhf(ev + d2[200 + p]) * v;
  }
  for (int off = 32; off; off >>= 1) {
    s0 += __shfl_down(s0, off);
    s1 += __shfl_down(s1, off);
  }
  if (lane == 0) {
    outp[((size_t)b * 2 + 0) * T + t] = s0;
    outp[((size_t)b * 2 + 1) * T + t] = s1;
  }
}

// ---------------- log_softmax over T, in-place ----------------
__global__ __launch_bounds__(256) void log_softmax_T(float* __restrict__ x, int T) {
  int row = blockIdx.x;
  float* p = x + (size_t)row * T;
  __shared__ float red[256];
  int tid = threadIdx.x;
  float m = -1e30f;
  for (int t = tid; t < T; t += 256) m = fmaxf(m, p[t]);
  red[tid] = m;
  __syncthreads();
  for (int s = 128; s; s >>= 1) {
    if (tid < s) red[tid] = fmaxf(red[tid], red[tid + s]);
    __syncthreads();
  }
  m = red[0];
  __syncthreads();
  float sum = 0.f;
  for (int t = tid; t < T; t += 256) sum += __expf(p[t] - m);
  red[tid] = sum;
  __syncthreads();
  for (int s = 128; s; s >>= 1) {
    if (tid < s) red[tid] += red[tid + s];
    __syncthreads();
  }
  float lse = m + __logf(red[0]);
  __syncthreads();
  for (int t = tid; t < T; t += 256) p[t] = p[t] - lse;
}

extern "C" void kernel_launch(void* const* d_in, const int* in_sizes, int n_in,
                              void* d_out, int out_size, void* d_ws, size_t ws_size,
                              hipStream_t stream) {
  (void)in_sizes; (void)n_in; (void)out_size; (void)ws_size;
  const int B = 32, T = 512, L = 64;
  const int BT = B * T;    // 16384
  const int BL = B * L;    // 2048

  const int* x_word = (const int*)d_in[0];
  const int* x_query = (const int*)d_in[1];
  const float* embed = (const float*)d_in[2];
  const float* ctx_wi = (const float*)d_in[3];
  const float* ctx_wh = (const float*)d_in[4];
  const float* ctx_bi = (const float*)d_in[5];
  const float* ctx_bh = (const float*)d_in[6];
  const float* mod0_wi = (const float*)d_in[7];
  const float* mod0_wh = (const float*)d_in[8];
  const float* mod0_bi = (const float*)d_in[9];
  const float* mod0_bh = (const float*)d_in[10];
  const float* mod1_wi = (const float*)d_in[11];
  const float* mod1_wh = (const float*)d_in[12];
  const float* mod1_bi = (const float*)d_in[13];
  const float* mod1_bh = (const float*)d_in[14];
  const float* w_sim = (const float*)d_in[15];
  const float* enc_wi = (const float*)d_in[16];
  const float* enc_wh = (const float*)d_in[17];
  const float* enc_bi = (const float*)d_in[18];
  const float* enc_bh = (const float*)d_in[19];
  const float* dec_wh = (const float*)d_in[21];
  const float* dec_bi = (const float*)d_in[22];
  const float* dec_bh = (const float*)d_in[23];
  const float* w1 = (const float*)d_in[24];
  const float* w2 = (const float*)d_in[25];
  const float* vt = (const float*)d_in[26];
  float* out_f = (float*)d_out;

  // ---- workspace layout (region reuse) ----
  char* ws = (char*)d_ws;
  size_t off = 0;
  auto alloc = [&](size_t bytes) -> void* {
    void* p = ws + off;
    off += (bytes + 255) & ~(size_t)255;
    return p;
  };
  u64* hx = (u64*)alloc((size_t)B * 2 * 400 * 8);  // tagged h-exchange words
  float* ew = (float*)alloc((size_t)BT * 100 * 4);
  float* eq = (float*)alloc((size_t)BL * 100 * 4);
  char* RA = (char*)alloc((size_t)BT * 1200 * 2);  // 39.3 MB
  bf16* xwA = (bf16*)RA;                            // [BT,300] bf16
  bf16* xwB = (bf16*)(RA + (size_t)BT * 300 * 2);
  bf16* xwe = (bf16*)RA;                            // [BT,1200] bf16 (later)
  bf16* xwqF = (bf16*)alloc((size_t)BL * 300 * 2);
  bf16* xwqB = (bf16*)alloc((size_t)BL * 300 * 2);
  char* RB = (char*)alloc((size_t)BT * 800 * 2);   // 26.2 MB
  bf16* G = (bf16*)RB;
  float* enc_out = (float*)RB;                      // [BT,400] f32 (later, same size)
  char* RC = (char*)alloc((size_t)2 * BT * 200 * 4);  // 26.2 MB
  float* h_cat = (float*)RC;                        // [BT,200]
  float* c2q = (float*)(RC + (size_t)BT * 200 * 4);
  float* M0 = c2q;                                  // reuse (c2q dead after G)
  float* Mx = h_cat;                                // reuse (h dead after G)
  float* encw1 = c2q;                               // reuse (M0 dead after xw1)
  float* u_cat = (float*)alloc((size_t)BL * 200 * 4);
  float* th = (float*)alloc((size_t)BT * 4);
  float* tu = (float*)alloc((size_t)BL * 4);
  float* smaxb = (float*)alloc((size_t)BT * 4);
  float* batt = (float*)alloc((size_t)BT * 4);
  float* q2cb = (float*)alloc((size_t)B * 200 * 4);
  float* d2 = (float*)alloc((size_t)400 * 4);

  // ---- 0. zero hx EVERY call (stale tags would satisfy polls across graph replays) ----
  hipMemsetAsync(hx, 0, (size_t)B * 2 * 400 * 8, stream);

  // ---- 1. embedding gathers ----
  gather_embed<<<(BT * 100 + 255) / 256, 256, 0, stream>>>(x_word, embed, ew, BT);
  gather_embed<<<(BL * 100 + 255) / 256, 256, 0, stream>>>(x_query, embed, eq, BL);

  // ---- 2. ctx input projections ----
  {
    dim3 g(BT / 64, (300 + 63) / 64);
    gemm_tn<float, bf16, true><<<g, 256, 0, stream>>>(ew, ctx_wi, ctx_bi, xwA, BT, 300, 100);
    gemm_tn<float, bf16, true><<<g, 256, 0, stream>>>(ew, ctx_wi + 30000, ctx_bi + 300, xwB, BT, 300, 100);
    dim3 gq(BL / 64, (300 + 63) / 64);
    gemm_tn<float, bf16, true><<<gq, 256, 0, stream>>>(eq, ctx_wi, ctx_bi, xwqF, BL, 300, 100);
    gemm_tn<float, bf16, true><<<gq, 256, 0, stream>>>(eq, ctx_wi + 30000, ctx_bi + 300, xwqB, BL, 300, 100);
  }

  // ---- 3. ctx scans (register-resident weights) ----
  gru_scan100_reg<<<dim3(B, 2), 320, 0, stream>>>(xwA, xwB, ctx_wh, ctx_bh, h_cat, T);
  gru_scan100_reg<<<dim3(B, 2), 320, 0, stream>>>(xwqF, xwqB, ctx_wh, ctx_bh, u_cat, L);

  // ---- 4. attention ----
  rowdot200<<<BT, 64, 0, stream>>>(h_cat, w_sim, th, BT);
  rowdot200<<<BL, 64, 0, stream>>>(u_cat, w_sim + 200, tu, BL);
  attn_main<<<dim3(B, T / 32), 256, 0, stream>>>(h_cat, u_cat, th, tu, w_sim, c2q, smaxb, T);
  softmax_T<<<B, 256, 0, stream>>>(smaxb, batt, T);
  q2c_kernel<<<B, 256, 0, stream>>>(batt, h_cat, q2cb, T);
  build_G<<<(BT * 200 + 255) / 256, 256, 0, stream>>>(h_cat, c2q, q2cb, G, T);

  // ---- 5. mod0 ----
  {
    dim3 g(BT / 64, (300 + 63) / 64);
    gemm_tn<bf16, bf16, true><<<g, 256, 0, stream>>>(G, mod0_wi, mod0_bi, xwA, BT, 300, 800);
    gemm_tn<bf16, bf16, true><<<g, 256, 0, stream>>>(G, mod0_wi + 240000, mod0_bi + 300, xwB, BT, 300, 800);
  }
  gru_scan100_reg<<<dim3(B, 2), 320, 0, stream>>>(xwA, xwB, mod0_wh, mod0_bh, M0, T);

  // ---- 6. mod1 ----
  {
    dim3 g(BT / 64, (300 + 63) / 64);
    gemm_tn<float, bf16, true><<<g, 256, 0, stream>>>(M0, mod1_wi, mod1_bi, xwA, BT, 300, 200);
    gemm_tn<float, bf16, true><<<g, 256, 0, stream>>>(M0, mod1_wi + 60000, mod1_bi + 300, xwB, BT, 300, 200);
  }
  gru_scan100_reg<<<dim3(B, 2), 320, 0, stream>>>(xwA, xwB, mod1_wh, mod1_bh, Mx, T);

  // ---- 7. encoder ----
  {
    dim3 g(BT / 64, (1200 + 63) / 64);
    gemm_tn<float, bf16, true><<<g, 256, 0, stream>>>(Mx, enc_wi, enc_bi, xwe, BT, 1200, 200);
  }
  gru_scan_enc_tag<<<dim3(B, 8), 640, 0, stream>>>(xwe, enc_wh, enc_bh, enc_out, hx, T);
  {
    dim3 g(BT / 64, (200 + 63) / 64);
    gemm_tn<float, float, false><<<g, 256, 0, stream>>>(enc_out, w1, nullptr, encw1, BT, 200, 400);
  }

  // ---- 8. pointer decoder ----
  decoder_small<<<1, 512, 0, stream>>>(dec_wh, dec_bi, dec_bh, w2, d2);
  logits_kernel<<<BT, 64, 0, stream>>>(encw1, d2, vt, out_f, T);
  log_softmax_T<<<B * 2, 256, 0, stream>>>(out_f, T);
}

// Round 6
// 3580.162 us; speedup vs baseline: 3.4443x; 1.1306x over previous
//
#include <hip/hip_runtime.h>
#include <hip/hip_bf16.h>

typedef __hip_bfloat16 bf16;
typedef unsigned long long u64;
typedef __attribute__((ext_vector_type(8))) short s8v;
typedef __attribute__((ext_vector_type(4))) short s4v;
typedef __attribute__((ext_vector_type(4))) float f4v;

#define DEV __device__ __forceinline__

DEV float to_f32(float x) { return x; }
DEV float to_f32(bf16 x) { return __bfloat162float(x); }
DEV void store_c(float* p, float v) { *p = v; }
DEV void store_c(bf16* p, float v) { *p = __float2bfloat16(v); }
DEV float sigmf(float x) { return 1.f / (1.f + __expf(-x)); }

// ---------------- embedding gather (bf16 out: feeds MFMA GEMM) ----------------
__global__ void gather_embed_bf(const int* __restrict__ idx, const float* __restrict__ embed,
                                bf16* __restrict__ out, int ntok) {
  int i = blockIdx.x * blockDim.x + threadIdx.x;
  if (i >= ntok * 100) return;
  int t = i / 100;
  int d = i - t * 100;
  out[i] = __float2bfloat16(embed[(size_t)idx[t] * 100 + d]);
}

// ---------------- f32 -> bf16 weight conversion ----------------
__global__ void cvt_bf16(const float* __restrict__ in, bf16* __restrict__ out, int n) {
  int i = blockIdx.x * blockDim.x + threadIdx.x;
  if (i < n) out[i] = __float2bfloat16(in[i]);
}

// ---------------- MFMA GEMM: C[M,N] = A[M,K]bf16 @ W[N,K]bf16^T (+bias f32) ------------
// M % 128 == 0. Tile 128x64, 4 waves (2x2), each wave 64x32 out = 4x2 frags of 16x16.
// v_mfma_f32_16x16x32_bf16 layouts (m89-verified): A: row=lane&15, k=8*(lane>>4)+j;
// B: col=lane&15, k=8*(lane>>4)+j; D: col=lane&15, row=4*(lane>>4)+reg.
// Both A and W rows are contiguous-k -> fragments are plain 16B vector loads (no transpose).
template <typename TC, bool HAS_BIAS>
__global__ __launch_bounds__(256) void gemm_mfma(
    const bf16* __restrict__ A, const bf16* __restrict__ W,
    const float* __restrict__ bias, TC* __restrict__ C,
    int M, int N, int K) {
  __shared__ short Als[128 * 32];  // [row][k] linear; wave frag read = distinct 16B/lane
  __shared__ short Wls[64 * 32];
  const int tid = threadIdx.x;
  const int m0 = blockIdx.x * 128;
  const int n0 = blockIdx.y * 64;
  const int lane = tid & 63;
  const int wv = tid >> 6;
  const int wm = wv >> 1, wn = wv & 1;
  const int lq = lane >> 4, lr = lane & 15;
  const int arow = tid >> 1;          // A staging: 128 rows x 2 threads
  const int ah = tid & 1;
  const int wrow = (tid & 127) >> 1;  // W staging: 64 rows x 2 threads (tid<128)

  f4v acc[4][2];
#pragma unroll
  for (int i = 0; i < 4; ++i)
#pragma unroll
    for (int j = 0; j < 2; ++j) acc[i][j] = (f4v){0.f, 0.f, 0.f, 0.f};

  for (int k0 = 0; k0 < K; k0 += 32) {
    // ---- stage A rows (slots of 8 k-elements; 8B loads: safe for K=100 odd-row align) ----
#pragma unroll
    for (int ss = 0; ss < 2; ++ss) {
      int s = 2 * ah + ss;
      int kk = k0 + s * 8;
      short* dst = &Als[arow * 32 + s * 8];
      const short* src = (const short*)(A + (size_t)(m0 + arow) * K + kk);
      if (kk + 8 <= K) {
        *(s4v*)dst = *(const s4v*)src;
        *(s4v*)(dst + 4) = *(const s4v*)(src + 4);
      } else {
#pragma unroll
        for (int j = 0; j < 8; ++j) dst[j] = (kk + j < K) ? src[j] : (short)0;
      }
    }
    // ---- stage W rows (guard n < N) ----
    if (tid < 128) {
      int nrow = n0 + wrow;
#pragma unroll
      for (int ss = 0; ss < 2; ++ss) {
        int s = 2 * (tid & 1) + ss;
        int kk = k0 + s * 8;
        short* dst = &Wls[wrow * 32 + s * 8];
        if (nrow < N) {
          const short* src = (const short*)(W + (size_t)nrow * K + kk);
          if (kk + 8 <= K) {
            *(s4v*)dst = *(const s4v*)src;
            *(s4v*)(dst + 4) = *(const s4v*)(src + 4);
          } else {
#pragma unroll
            for (int j = 0; j < 8; ++j) dst[j] = (kk + j < K) ? src[j] : (short)0;
          }
        } else {
#pragma unroll
          for (int j = 0; j < 8; ++j) dst[j] = (short)0;
        }
      }
    }
    __syncthreads();
    s8v af[4], bfr[2];
#pragma unroll
    for (int mi = 0; mi < 4; ++mi) {
      int r = wm * 64 + mi * 16 + lr;
      af[mi] = *(const s8v*)&Als[r * 32 + lq * 8];
    }
#pragma unroll
    for (int ni = 0; ni < 2; ++ni) {
      int r = wn * 32 + ni * 16 + lr;
      bfr[ni] = *(const s8v*)&Wls[r * 32 + lq * 8];
    }
#pragma unroll
    for (int mi = 0; mi < 4; ++mi)
#pragma unroll
      for (int ni = 0; ni < 2; ++ni)
        acc[mi][ni] = __builtin_amdgcn_mfma_f32_16x16x32_bf16(af[mi], bfr[ni], acc[mi][ni], 0, 0, 0);
    __syncthreads();
  }
  // ---- epilogue ----
#pragma unroll
  for (int mi = 0; mi < 4; ++mi) {
#pragma unroll
    for (int ni = 0; ni < 2; ++ni) {
      int n = n0 + wn * 32 + ni * 16 + lr;
      if (n >= N) continue;
      float bv = HAS_BIAS ? bias[n] : 0.f;
#pragma unroll
      for (int r = 0; r < 4; ++r) {
        int m = m0 + wm * 64 + mi * 16 + lq * 4 + r;
        store_c(&C[(size_t)m * N + n], acc[mi][ni][r] + bv);
      }
    }
  }
}

// ---------------- GRU scan H=100, register-resident weights, one WG per (batch,dir) --------
template <typename TO>
__global__ __launch_bounds__(320) void gru_scan100_reg(
    const bf16* __restrict__ xw_f, const bf16* __restrict__ xw_b,
    const float* __restrict__ wh,  // [2][300][100] (raw layout)
    const float* __restrict__ bh,  // [2][300]
    TO* __restrict__ out,          // [B,T,200]
    int T) {
  const int b = blockIdx.x, dir = blockIdx.y;
  const bf16* xw = dir ? xw_b : xw_f;
  __shared__ float h_s[100];
  __shared__ float g_s[300];
  const int tid = threadIdx.x;
  float w[100];
  float bias = 0.f;
  if (tid < 300) {
    const float* wrow = wh + (size_t)dir * 30000 + (size_t)tid * 100;
#pragma unroll
    for (int c = 0; c < 25; ++c) {
      float4 v = *(const float4*)(wrow + 4 * c);
      w[4 * c] = v.x; w[4 * c + 1] = v.y; w[4 * c + 2] = v.z; w[4 * c + 3] = v.w;
    }
    bias = bh[dir * 300 + tid];
  }
  if (tid < 100) h_s[tid] = 0.f;
  __syncthreads();
  for (int step = 0; step < T; ++step) {
    int t = dir ? (T - 1 - step) : step;
    if (tid < 300) {
      float a0 = bias, a1 = 0.f, a2 = 0.f, a3 = 0.f;
#pragma unroll
      for (int c = 0; c < 25; ++c) {
        float4 h4 = *(const float4*)(&h_s[4 * c]);
        a0 += w[4 * c] * h4.x; a1 += w[4 * c + 1] * h4.y;
        a2 += w[4 * c + 2] * h4.z; a3 += w[4 * c + 3] * h4.w;
      }
      g_s[tid] = (a0 + a1) + (a2 + a3);
    }
    __syncthreads();
    if (tid < 100) {
      size_t base = ((size_t)b * T + t) * 300;
      float xr = to_f32(xw[base + tid]);
      float xz = to_f32(xw[base + 100 + tid]);
      float xn = to_f32(xw[base + 200 + tid]);
      float rr = sigmf(xr + g_s[tid]);
      float zz = sigmf(xz + g_s[100 + tid]);
      float nn = tanhf(xn + rr * g_s[200 + tid]);
      float hn = (1.f - zz) * nn + zz * h_s[tid];
      h_s[tid] = hn;
      store_c(&out[((size_t)b * T + t) * 200 + dir * 100 + tid], hn);
    }
    __syncthreads();
  }
}

// ---------------- encoder GRU scan H=400: 8 WGs/batch, tagged exchange + xw prefetch -------
__global__ __launch_bounds__(640) void gru_scan_enc_tag(
    const bf16* __restrict__ xw,   // [B,T,1200]
    const float* __restrict__ wh,  // [1200,400] raw
    const float* __restrict__ bh,  // [1200]
    bf16* __restrict__ out,        // [B,T,400] (feeds w1 MFMA GEMM)
    u64* __restrict__ hx,          // [B,2,400] {value,tag} words (pre-zeroed EVERY call)
    int T) {
  const int b = blockIdx.x, s = blockIdx.y;
  __shared__ float h_s[400];
  __shared__ float g_s[150];
  const int tid = threadIdx.x;
  const int g = tid >> 2, p = tid & 3;  // gate g in [0,150), k-quarter p
  const bool active = (tid < 600);
  float w[100];
  float bias = 0.f;
  if (active) {
    int i = g % 50, grp = g / 50;  // grp: 0=r 1=z 2=n
    int gidx = grp * 400 + s * 50 + i;
    const float* wrow = wh + (size_t)gidx * 400 + p * 100;
#pragma unroll
    for (int c = 0; c < 25; ++c) {
      float4 v = *(const float4*)(wrow + 4 * c);
      w[4 * c] = v.x; w[4 * c + 1] = v.y; w[4 * c + 2] = v.z; w[4 * c + 3] = v.w;
    }
    if (p == 0) bias = bh[gidx];
  }
  for (int k = tid; k < 400; k += 640) h_s[k] = 0.f;
  // prefetch xw for t=0 (off the critical path: gate compute doesn't need xw)
  const int myi = s * 50 + tid;
  float pxr = 0.f, pxz = 0.f, pxn = 0.f;
  if (tid < 50) {
    size_t base0 = (size_t)b * T * 1200;
    pxr = to_f32(xw[base0 + myi]);
    pxz = to_f32(xw[base0 + 400 + myi]);
    pxn = to_f32(xw[base0 + 800 + myi]);
  }
  __syncthreads();

  for (int t = 0; t < T; ++t) {
    if (active) {
      float a0 = bias, a1 = 0.f, a2 = 0.f, a3 = 0.f;
      const int hb = p * 100;
#pragma unroll
      for (int c = 0; c < 25; ++c) {
        float4 h4 = *(const float4*)(&h_s[hb + 4 * c]);
        a0 += w[4 * c] * h4.x; a1 += w[4 * c + 1] * h4.y;
        a2 += w[4 * c + 2] * h4.z; a3 += w[4 * c + 3] * h4.w;
      }
      float acc = (a0 + a1) + (a2 + a3);
      acc += __shfl_xor(acc, 1);
      acc += __shfl_xor(acc, 2);
      if (p == 0) g_s[g] = acc;
    }
    __syncthreads();  // gates ready; everyone done READING h_s
    const int par = (t + 1) & 1;
    u64* hxp = hx + ((size_t)b * 2 + par) * 400;
    if (tid < 50) {
      float rr = sigmf(pxr + g_s[tid]);
      float zz = sigmf(pxz + g_s[50 + tid]);
      float nn = tanhf(pxn + rr * g_s[100 + tid]);
      float hn = (1.f - zz) * nn + zz * h_s[myi];
      out[((size_t)b * T + t) * 400 + myi] = __float2bfloat16(hn);
      h_s[myi] = hn;  // local copy
      u64 pack = (u64)__float_as_uint(hn) | ((u64)(unsigned)(t + 1) << 32);
      __hip_atomic_store(&hxp[myi], pack, __ATOMIC_RELAXED, __HIP_MEMORY_SCOPE_AGENT);
      // prefetch xw for t+1: ~900cy HBM latency hides under the poll below
      if (t + 1 < T) {
        size_t basen = ((size_t)b * T + (t + 1)) * 1200;
        pxr = to_f32(xw[basen + myi]);
        pxz = to_f32(xw[basen + 400 + myi]);
        pxn = to_f32(xw[basen + 800 + myi]);
      }
    }
    if (tid < 400 && (tid / 50) != s) {
      const u64* src = &hxp[tid];
      u64 v;
      for (;;) {
        v = __hip_atomic_load(src, __ATOMIC_RELAXED, __HIP_MEMORY_SCOPE_AGENT);
        if ((unsigned)(v >> 32) == (unsigned)(t + 1)) break;
        __builtin_amdgcn_s_sleep(1);
      }
      h_s[tid] = __uint_as_float((unsigned)v);
    }
    __syncthreads();  // full h(t+1) assembled in h_s
  }
}

// ---------------- row · w (200-dim) -> scalar; one wave per row ----------------
__global__ __launch_bounds__(64) void rowdot200(const float* __restrict__ X, const float* __restrict__ w,
                                                float* __restrict__ out, int rows) {
  int r = blockIdx.x;
  int lane = threadIdx.x;
  const float* x = X + (size_t)r * 200;
  float s = x[lane] * w[lane] + x[lane + 64] * w[lane + 64] + x[lane + 128] * w[lane + 128];
  if (lane < 8) s += x[lane + 192] * w[lane + 192];
  for (int off = 32; off; off >>= 1) s += __shfl_down(s, off);
  if (lane == 0) out[r] = s;
}

// ---------------- attention: S row softmax -> c2q, row max -> smax ----------------
__global__ __launch_bounds__(256) void attn_main(
    const float* __restrict__ h,      // [B,T,200]
    const float* __restrict__ u,      // [B,64,200]
    const float* __restrict__ th,     // [B,T]
    const float* __restrict__ tu,     // [B,64]
    const float* __restrict__ w_sim,  // w3s at +400
    float* __restrict__ c2q,          // [B,T,200]
    float* __restrict__ smax,         // [B,T]
    int T) {
  const int b = blockIdx.x;
  const int t0 = blockIdx.y * 32;
  __shared__ float u_s[64 * 201];
  __shared__ float tu_s[64];
  __shared__ float w3_s[200];
  __shared__ float hw3_s[200];
  __shared__ float Sp[4][64];
  __shared__ float A_s[64];
  const int tid = threadIdx.x;
  for (int i = tid; i < 64 * 200; i += 256) {
    int l = i / 200, d = i - l * 200;
    u_s[l * 201 + d] = u[((size_t)b * 64 + l) * 200 + d];
  }
  if (tid < 64) tu_s[tid] = tu[b * 64 + tid];
  if (tid < 200) w3_s[tid] = w_sim[400 + tid];
  __syncthreads();
  for (int tt = 0; tt < 32; ++tt) {
    int t = t0 + tt;
    if (tid < 200) hw3_s[tid] = h[((size_t)b * T + t) * 200 + tid] * w3_s[tid];
    __syncthreads();
    int l = tid & 63, q = tid >> 6;
    float p = 0.f;
    for (int d = q * 50; d < q * 50 + 50; ++d) p += hw3_s[d] * u_s[l * 201 + d];
    Sp[q][l] = p;
    __syncthreads();
    if (tid < 64) {
      float s = th[b * T + t] + tu_s[l] + Sp[0][l] + Sp[1][l] + Sp[2][l] + Sp[3][l];
      float m = s;
      for (int off = 32; off; off >>= 1) m = fmaxf(m, __shfl_xor(m, off));
      float e = __expf(s - m);
      float ssum = e;
      for (int off = 32; off; off >>= 1) ssum += __shfl_xor(ssum, off);
      A_s[l] = e / ssum;
      if (l == 0) smax[b * T + t] = m;
    }
    __syncthreads();
    if (tid < 200) {
      float acc = 0.f;
      for (int l2 = 0; l2 < 64; ++l2) acc += A_s[l2] * u_s[l2 * 201 + tid];
      c2q[((size_t)b * T + t) * 200 + tid] = acc;
    }
    __syncthreads();
  }
}

// ---------------- softmax over T (per batch row) ----------------
__global__ __launch_bounds__(256) void softmax_T(const float* __restrict__ in, float* __restrict__ outv, int T) {
  int b = blockIdx.x;
  int tid = threadIdx.x;
  __shared__ float red[256];
  float m = -1e30f;
  for (int t = tid; t < T; t += 256) m = fmaxf(m, in[b * T + t]);
  red[tid] = m;
  __syncthreads();
  for (int s = 128; s; s >>= 1) {
    if (tid < s) red[tid] = fmaxf(red[tid], red[tid + s]);
    __syncthreads();
  }
  m = red[0];
  __syncthreads();
  float sum = 0.f;
  for (int t = tid; t < T; t += 256) sum += __expf(in[b * T + t] - m);
  red[tid] = sum;
  __syncthreads();
  for (int s = 128; s; s >>= 1) {
    if (tid < s) red[tid] += red[tid + s];
    __syncthreads();
  }
  float inv = 1.f / red[0];
  for (int t = tid; t < T; t += 256) outv[b * T + t] = __expf(in[b * T + t] - m) * inv;
}

// ---------------- q2c[b,d] = sum_t batt[b,t] * h[b,t,d] ----------------
__global__ __launch_bounds__(256) void q2c_kernel(const float* __restrict__ batt, const float* __restrict__ h,
                                                  float* __restrict__ q2c, int T) {
  int b = blockIdx.x;
  int tid = threadIdx.x;
  if (tid < 200) {
    float acc = 0.f;
    for (int t = 0; t < T; ++t) acc += batt[b * T + t] * h[((size_t)b * T + t) * 200 + tid];
    q2c[b * 200 + tid] = acc;
  }
}

// ---------------- G = [h, c2q, h*c2q, h*q2c] (bf16) ----------------
__global__ void build_G(const float* __restrict__ h, const float* __restrict__ c2q,
                        const float* __restrict__ q2c, bf16* __restrict__ G, int T) {
  size_t i = (size_t)blockIdx.x * blockDim.x + threadIdx.x;
  if (i >= (size_t)32 * T * 200) return;
  size_t row = i / 200;
  int d = (int)(i - row * 200);
  int b = (int)(row / T);
  float hv = h[i];
  float cv = c2q[i];
  float qv = q2c[b * 200 + d];
  bf16* g = G + row * 800;
  g[d] = __float2bfloat16(hv);
  g[200 + d] = __float2bfloat16(cv);
  g[400 + d] = __float2bfloat16(hv * cv);
  g[600 + d] = __float2bfloat16(hv * qv);
}

// ---------------- decoder (batch-uniform since dec_in == 0): d2[2][200] ----------------
__global__ __launch_bounds__(512) void decoder_small(
    const float* __restrict__ dwh,  // [1200,400]
    const float* __restrict__ dbi, const float* __restrict__ dbh,
    const float* __restrict__ w2,  // [200,400]
    float* __restrict__ d2out) {   // [2][200]
  __shared__ float hid[400];
  __shared__ float hid2[400];
  __shared__ float gh[1200];
  const int tid = threadIdx.x;
  if (tid < 400) {
    float r = sigmf(dbi[tid] + dbh[tid]);
    float z = sigmf(dbi[400 + tid] + dbh[400 + tid]);
    float n = tanhf(dbi[800 + tid] + r * dbh[800 + tid]);
    hid[tid] = (1.f - z) * n;
  }
  __syncthreads();
  if (tid < 200) {
    float a = 0.f;
    for (int k = 0; k < 400; ++k) a += w2[(size_t)tid * 400 + k] * hid[k];
    d2out[tid] = a;
  }
  for (int j = tid; j < 1200; j += 512) {
    float a = dbh[j];
    for (int k = 0; k < 400; ++k) a += dwh[(size_t)j * 400 + k] * hid[k];
    gh[j] = a;
  }
  __syncthreads();
  if (tid < 400) {
    float r = sigmf(dbi[tid] + gh[tid]);
    float z = sigmf(dbi[400 + tid] + gh[400 + tid]);
    float n = tanhf(dbi[800 + tid] + r * gh[800 + tid]);
    hid2[tid] = (1.f - z) * n + z * hid[tid];
  }
  __syncthreads();
  if (tid < 200) {
    float a = 0.f;
    for (int k = 0; k < 400; ++k) a += w2[(size_t)tid * 400 + k] * hid2[k];
    d2out[200 + tid] = a;
  }
}

// ---------------- logits: out[b,it,t] = sum_p tanh(encw1[b,t,p]+d2[it][p])*vt[p] ----------------
__global__ __launch_bounds__(64) void logits_kernel(
    const float* __restrict__ encw1,  // [B,T,200]
    const float* __restrict__ d2,     // [2][200]
    const float* __restrict__ vt,     // [200]
    float* __restrict__ outp,         // [B,2,T]
    int T) {
  int row = blockIdx.x;  // b*T + t
  int b = row / T, t = row - b * T;
  int lane = threadIdx.x;
  const float* e = encw1 + (size_t)row * 200;
  float s0 = 0.f, s1 = 0.f;
  for (int p = lane; p < 200; p += 64) {
    float ev = e[p], v = vt[p];
    s0 += tanhf(ev + d2[p]) * v;
    s1 += tanhf(ev + d2[200 + p]) * v;
  }
  for (int off = 32; off; off >>= 1) {
    s0 += __shfl_down(s0, off);
    s1 += __shfl_down(s1, off);
  }
  if (lane == 0) {
    outp[((size_t)b * 2 + 0) * T + t] = s0;
    outp[((size_t)b * 2 + 1) * T + t] = s1;
  }
}

// ---------------- log_softmax over T, in-place ----------------
__global__ __launch_bounds__(256) void log_softmax_T(float* __restrict__ x, int T) {
  int row = blockIdx.x;
  float* p = x + (size_t)row * T;
  __shared__ float red[256];
  int tid = threadIdx.x;
  float m = -1e30f;
  for (int t = tid; t < T; t += 256) m = fmaxf(m, p[t]);
  red[tid] = m;
  __syncthreads();
  for (int s = 128; s; s >>= 1) {
    if (tid < s) red[tid] = fmaxf(red[tid], red[tid + s]);
    __syncthreads();
  }
  m = red[0];
  __syncthreads();
  float sum = 0.f;
  for (int t = tid; t < T; t += 256) sum += __expf(p[t] - m);
  red[tid] = sum;
  __syncthreads();
  for (int s = 128; s; s >>= 1) {
    if (tid < s) red[tid] += red[tid + s];
    __syncthreads();
  }
  float lse = m + __logf(red[0]);
  __syncthreads();
  for (int t = tid; t < T; t += 256) p[t] = p[t] - lse;
}

extern "C" void kernel_launch(void* const* d_in, const int* in_sizes, int n_in,
                              void* d_out, int out_size, void* d_ws, size_t ws_size,
                              hipStream_t stream) {
  (void)in_sizes; (void)n_in; (void)out_size; (void)ws_size;
  const int B = 32, T = 512, L = 64;
  const int BT = B * T;    // 16384
  const int BL = B * L;    // 2048

  const int* x_word = (const int*)d_in[0];
  const int* x_query = (const int*)d_in[1];
  const float* embed = (const float*)d_in[2];
  const float* ctx_wi = (const float*)d_in[3];
  const float* ctx_wh = (const float*)d_in[4];
  const float* ctx_bi = (const float*)d_in[5];
  const float* ctx_bh = (const float*)d_in[6];
  const float* mod0_wi = (const float*)d_in[7];
  const float* mod0_wh = (const float*)d_in[8];
  const float* mod0_bi = (const float*)d_in[9];
  const float* mod0_bh = (const float*)d_in[10];
  const float* mod1_wi = (const float*)d_in[11];
  const float* mod1_wh = (const float*)d_in[12];
  const float* mod1_bi = (const float*)d_in[13];
  const float* mod1_bh = (const float*)d_in[14];
  const float* w_sim = (const float*)d_in[15];
  const float* enc_wi = (const float*)d_in[16];
  const float* enc_wh = (const float*)d_in[17];
  const float* enc_bi = (const float*)d_in[18];
  const float* enc_bh = (const float*)d_in[19];
  const float* dec_wh = (const float*)d_in[21];
  const float* dec_bi = (const float*)d_in[22];
  const float* dec_bh = (const float*)d_in[23];
  const float* w1 = (const float*)d_in[24];
  const float* w2 = (const float*)d_in[25];
  const float* vt = (const float*)d_in[26];
  float* out_f = (float*)d_out;

  // ---- workspace layout (region reuse) ----
  char* ws = (char*)d_ws;
  size_t off = 0;
  auto alloc = [&](size_t bytes) -> void* {
    void* p = ws + off;
    off += (bytes + 255) & ~(size_t)255;
    return p;
  };
  u64* hx = (u64*)alloc((size_t)B * 2 * 400 * 8);  // tagged h-exchange words
  bf16* ewbf = (bf16*)alloc((size_t)BT * 100 * 2);
  bf16* eqbf = (bf16*)alloc((size_t)BL * 100 * 2);
  bf16* ctx_wibf = (bf16*)alloc((size_t)60000 * 2);
  bf16* mod0_wibf = (bf16*)alloc((size_t)480000 * 2);
  bf16* mod1_wibf = (bf16*)alloc((size_t)120000 * 2);
  bf16* enc_wibf = (bf16*)alloc((size_t)240000 * 2);
  bf16* w1bf = (bf16*)alloc((size_t)80000 * 2);
  char* RA = (char*)alloc((size_t)BT * 1200 * 2);  // 39.3 MB
  bf16* xwA = (bf16*)RA;                            // [BT,300] bf16
  bf16* xwB = (bf16*)(RA + (size_t)BT * 300 * 2);
  bf16* xwe = (bf16*)RA;                            // [BT,1200] bf16 (later)
  bf16* xwqF = (bf16*)alloc((size_t)BL * 300 * 2);
  bf16* xwqB = (bf16*)alloc((size_t)BL * 300 * 2);
  char* RB = (char*)alloc((size_t)BT * 800 * 2);   // 26.2 MB
  bf16* G = (bf16*)RB;
  bf16* enc_outbf = (bf16*)RB;                      // [BT,400] bf16 (after G dead)
  char* RC = (char*)alloc((size_t)2 * BT * 200 * 4);  // 26.2 MB
  float* h_cat = (float*)RC;                        // [BT,200] f32 (attention path)
  float* c2q = (float*)(RC + (size_t)BT * 200 * 4);
  bf16* M0bf = (bf16*)c2q;                          // reuse (c2q dead after G)
  bf16* Mxbf = (bf16*)h_cat;                        // reuse (h dead after G)
  float* encw1 = c2q;                               // reuse (M0bf dead after mod1 GEMM)
  float* u_cat = (float*)alloc((size_t)BL * 200 * 4);
  float* th = (float*)alloc((size_t)BT * 4);
  float* tu = (float*)alloc((size_t)BL * 4);
  float* smaxb = (float*)alloc((size_t)BT * 4);
  float* batt = (float*)alloc((size_t)BT * 4);
  float* q2cb = (float*)alloc((size_t)B * 200 * 4);
  float* d2 = (float*)alloc((size_t)400 * 4);

  // ---- 0. zero hx EVERY call (stale tags would satisfy polls across graph replays) ----
  hipMemsetAsync(hx, 0, (size_t)B * 2 * 400 * 8, stream);

  // ---- 1. weight f32->bf16 conversions + embedding gathers ----
  cvt_bf16<<<(60000 + 255) / 256, 256, 0, stream>>>(ctx_wi, ctx_wibf, 60000);
  cvt_bf16<<<(480000 + 255) / 256, 256, 0, stream>>>(mod0_wi, mod0_wibf, 480000);
  cvt_bf16<<<(120000 + 255) / 256, 256, 0, stream>>>(mod1_wi, mod1_wibf, 120000);
  cvt_bf16<<<(240000 + 255) / 256, 256, 0, stream>>>(enc_wi, enc_wibf, 240000);
  cvt_bf16<<<(80000 + 255) / 256, 256, 0, stream>>>(w1, w1bf, 80000);
  gather_embed_bf<<<(BT * 100 + 255) / 256, 256, 0, stream>>>(x_word, embed, ewbf, BT);
  gather_embed_bf<<<(BL * 100 + 255) / 256, 256, 0, stream>>>(x_query, embed, eqbf, BL);

  // ---- 2. ctx input projections (MFMA, K=100) ----
  {
    dim3 g(BT / 128, (300 + 63) / 64);
    gemm_mfma<bf16, true><<<g, 256, 0, stream>>>(ewbf, ctx_wibf, ctx_bi, xwA, BT, 300, 100);
    gemm_mfma<bf16, true><<<g, 256, 0, stream>>>(ewbf, ctx_wibf + 30000, ctx_bi + 300, xwB, BT, 300, 100);
    dim3 gq(BL / 128, (300 + 63) / 64);
    gemm_mfma<bf16, true><<<gq, 256, 0, stream>>>(eqbf, ctx_wibf, ctx_bi, xwqF, BL, 300, 100);
    gemm_mfma<bf16, true><<<gq, 256, 0, stream>>>(eqbf, ctx_wibf + 30000, ctx_bi + 300, xwqB, BL, 300, 100);
  }

  // ---- 3. ctx scans (register-resident weights; f32 out for attention) ----
  gru_scan100_reg<float><<<dim3(B, 2), 320, 0, stream>>>(xwA, xwB, ctx_wh, ctx_bh, h_cat, T);
  gru_scan100_reg<float><<<dim3(B, 2), 320, 0, stream>>>(xwqF, xwqB, ctx_wh, ctx_bh, u_cat, L);

  // ---- 4. attention ----
  rowdot200<<<BT, 64, 0, stream>>>(h_cat, w_sim, th, BT);
  rowdot200<<<BL, 64, 0, stream>>>(u_cat, w_sim + 200, tu, BL);
  attn_main<<<dim3(B, T / 32), 256, 0, stream>>>(h_cat, u_cat, th, tu, w_sim, c2q, smaxb, T);
  softmax_T<<<B, 256, 0, stream>>>(smaxb, batt, T);
  q2c_kernel<<<B, 256, 0, stream>>>(batt, h_cat, q2cb, T);
  build_G<<<(BT * 200 + 255) / 256, 256, 0, stream>>>(h_cat, c2q, q2cb, G, T);

  // ---- 5. mod0 (MFMA K=800) ----
  {
    dim3 g(BT / 128, (300 + 63) / 64);
    gemm_mfma<bf16, true><<<g, 256, 0, stream>>>(G, mod0_wibf, mod0_bi, xwA, BT, 300, 800);
    gemm_mfma<bf16, true><<<g, 256, 0, stream>>>(G, mod0_wibf + 240000, mod0_bi + 300, xwB, BT, 300, 800);
  }
  gru_scan100_reg<bf16><<<dim3(B, 2), 320, 0, stream>>>(xwA, xwB, mod0_wh, mod0_bh, M0bf, T);

  // ---- 6. mod1 (MFMA K=200) ----
  {
    dim3 g(BT / 128, (300 + 63) / 64);
    gemm_mfma<bf16, true><<<g, 256, 0, stream>>>(M0bf, mod1_wibf, mod1_bi, xwA, BT, 300, 200);
    gemm_mfma<bf16, true><<<g, 256, 0, stream>>>(M0bf, mod1_wibf + 60000, mod1_bi + 300, xwB, BT, 300, 200);
  }
  gru_scan100_reg<bf16><<<dim3(B, 2), 320, 0, stream>>>(xwA, xwB, mod1_wh, mod1_bh, Mxbf, T);

  // ---- 7. encoder (MFMA K=200, N=1200) ----
  {
    dim3 g(BT / 128, (1200 + 63) / 64);
    gemm_mfma<bf16, true><<<g, 256, 0, stream>>>(Mxbf, enc_wibf, enc_bi, xwe, BT, 1200, 200);
  }
  gru_scan_enc_tag<<<dim3(B, 8), 640, 0, stream>>>(xwe, enc_wh, enc_bh, enc_outbf, hx, T);
  {
    dim3 g(BT / 128, (200 + 63) / 64);
    gemm_mfma<float, false><<<g, 256, 0, stream>>>(enc_outbf, w1bf, nullptr, encw1, BT, 200, 400);
  }

  // ---- 8. pointer decoder ----
  decoder_small<<<1, 512, 0, stream>>>(dec_wh, dec_bi, dec_bh, w2, d2);
  logits_kernel<<<BT, 64, 0, stream>>>(encw1, d2, vt, out_f, T);
  log_softmax_T<<<B * 2, 256, 0, stream>>>(out_f, T);
}